// Round 1
// 1977.911 us; speedup vs baseline: 1.6203x; 1.6203x over previous
//
#include <hip/hip_runtime.h>
#include <hip/hip_bf16.h>
#include <math.h>

typedef __hip_bfloat16 bf16;
typedef unsigned long long u64;
typedef unsigned int u32;

#define LTT 4
#define DIM 256
#define NTOK 32768      // total tokens (4*8*1024)
#define MT 2097152      // elements per time step (8192 tokens * 256)
#define NTOT 8388608

typedef __attribute__((ext_vector_type(8))) short short8;   // 8 bf16 (4 VGPRs)
typedef __attribute__((ext_vector_type(4))) float f32x4;

// dual-dtype load with finite clamp: f=1 -> fp32, f=0 -> bf16
__device__ __forceinline__ float ldin(const void* p, size_t i, int f) {
  float v = f ? ((const float*)p)[i] : __bfloat162float(((const bf16*)p)[i]);
  return isfinite(v) ? v : 0.0f;
}

// ---------------- per-input dtype probe ----------------
__global__ void probe1_k(const void* p, int nelem, int* flag) {
  int tid = threadIdx.x;  // 64
  const unsigned short* u = (const unsigned short*)p;
  int n = nelem < 1024 ? nelem : 1024;
  bool big = false, nz = false;
  for (int i = tid; i < n; i += 64) {
    unsigned short h = u[i];
    if (((h >> 7) & 0xFF) >= 0xC0) big = true;
    if (h != 0) nz = true;
  }
  u64 bm = __ballot(big);
  u64 zm = __ballot(nz);
  if (tid == 0) {
    unsigned short h0 = u[0];
    int f = 0;
    if (bm != 0ull) f = 1;
    else if (h0 == 0 && (zm != 0ull || n == 1)) f = 1;
    *flag = f;
  }
}

__global__ void setone_k(int* p) { *p = 1; }

// ---------------- batchnorm stats: per-channel sums over 32768 tokens ----------------
__global__ void bnstats_k(const void* __restrict__ x, const int* __restrict__ fxp,
                          float* __restrict__ gsum, float* __restrict__ gsq) {
  int fx = *fxp;
  int c = threadIdx.x;            // 256 channels
  int tok0 = blockIdx.x * 128;    // 256 blocks * 128 tokens
  float s = 0.f, q = 0.f;
  for (int t = 0; t < 128; t++) {
    float v = ldin(x, (size_t)(tok0 + t) * DIM + c, fx);
    s += v; q += v * v;
  }
  atomicAdd(&gsum[c], s);
  atomicAdd(&gsq[c], q);
}

// ---------------- fused BN-apply + LIF scan over t; spikes bit-packed ----------------
__global__ void lif_k(const void* __restrict__ x, const int* __restrict__ fxp,
                      const float* __restrict__ gsum, const float* __restrict__ gsq,
                      const void* __restrict__ gamma, const int* __restrict__ fgp,
                      const void* __restrict__ beta, const int* __restrict__ fbp,
                      u64* __restrict__ bits) {
  int fx = *fxp, fg = *fgp, fb = *fbp;
  int m = blockIdx.x * 256 + threadIdx.x;   // [0, MT)
  int c = m & (DIM - 1);
  int lane = threadIdx.x & 63;
  float mean = gsum[c] * (1.0f / 32768.0f);
  float var  = gsq[c] * (1.0f / 32768.0f) - mean * mean;
  float inv  = rsqrtf(var + 1e-5f);
  float g = ldin(gamma, c, fg), be = ldin(beta, c, fb);
  float v = 0.f;
  #pragma unroll
  for (int t = 0; t < LTT; t++) {
    size_t e = (size_t)t * MT + m;
    float xn = (ldin(x, e, fx) - mean) * inv * g + be;
    v = v + (xn - v) * 0.5f;                 // TAU = 2
    bool sp = (v - 1.0f >= 0.0f);            // VTH = 1
    u64 bl = __ballot(sp);
    if (lane == 0) bits[e >> 6] = bl;        // e>>6 is wave-uniform
    v = sp ? 0.0f : v;
  }
}

__device__ __forceinline__ float gelu_f(float x) {
  return 0.5f * x * (1.0f + erff(x * 0.70710678118654752440f));
}

// ---------------- one-time weight convert+transpose: W[K][N] (flag dtype) -> Wt[N][K] bf16 ----
// grid: dim3(K/256, N); reads are uncoalesced but one-time & L2-resident (<=1MB each).
__global__ void wconv_k(const void* __restrict__ W, const int* __restrict__ fp,
                        bf16* __restrict__ Wt, int K, int N) {
  int f = *fp;
  int k = blockIdx.x * 256 + threadIdx.x;
  int n = blockIdx.y;
  Wt[(size_t)n * K + k] = __float2bfloat16(ldin(W, (size_t)k * N + n, f));
}

// ---------------- MFMA bf16 GEMM, 128x128 tile, BK=32, 4 waves ----------------
// A: AF=0 bf16 row-major [M][K]; AF=2 bit-packed spikes (u32 view, 8 u32/row @K=256).
// B: Bt = pre-transposed bf16 [N][K].
// MODE 2: O(bf16) = gelu(acc+bias)
// MODE 3: O(bf16) = acc+bias
// MODE 4: Of32[obase+o] = xin[obase+o] + scl*(acc+bias)  (FFN2 aliases O==xin,
//         same element same thread -> O/xinv NOT __restrict__)
// LDS layout [kb][row][8] (16B units): fragment ds_read_b128 spreads evenly over
// all 32 banks (row*4 mod 32), no 8-way conflicts of a plain [row][k] layout.
template <int MODE, int AF>
__global__ void __launch_bounds__(256)
mgemm_k(const void* __restrict__ Av,
        const bf16* __restrict__ Bt,
        const void* __restrict__ biasv, const int* __restrict__ fbp,
        void* O, const void* xinv, const int* __restrict__ fxp,
        const void* __restrict__ scalev, const int* __restrict__ fsp,
        int N, int K, size_t obase) {
  __shared__ __align__(16) short As2[4][128][8];   // 8 KB
  __shared__ __align__(16) short Bs2[4][128][8];   // 8 KB
  const bf16* Ab = (const bf16*)Av;
  const u32* Abits = (const u32*)Av;
  int tid = threadIdx.x;
  int bm = blockIdx.y * 128, bn = blockIdx.x * 128;
  int lane = tid & 63, w = tid >> 6;
  int wr = w >> 1, wc = w & 1;          // wave -> 64x64 quadrant
  int kq = lane >> 4, lr = lane & 15;
  f32x4 acc[4][4] = {};

  for (int k0 = 0; k0 < K; k0 += 32) {
    // stage A tile -> As2[kb][m][8]
    #pragma unroll
    for (int ch = tid; ch < 512; ch += 256) {
      int m = ch >> 2, kb = ch & 3;
      short8 v;
      if (AF == 2) {
        u32 wb = Abits[(size_t)(bm + m) * (K >> 5) + (k0 >> 5)];
        u32 byte = (wb >> (kb * 8)) & 0xFFu;
        #pragma unroll
        for (int j = 0; j < 8; j++)
          v[j] = (short)(((byte >> j) & 1u) ? 0x3F80 : 0);
      } else {
        v = *(const short8*)&Ab[(size_t)(bm + m) * K + k0 + kb * 8];
      }
      *(short8*)&As2[kb][m][0] = v;
    }
    // stage B tile -> Bs2[kb][n][8]  (Bt row-major [N][K]: contiguous 16B reads)
    #pragma unroll
    for (int ch = tid; ch < 512; ch += 256) {
      int n = ch >> 2, kb = ch & 3;
      *(short8*)&Bs2[kb][n][0] =
          *(const short8*)&Bt[(size_t)(bn + n) * K + k0 + kb * 8];
    }
    __syncthreads();

    short8 af[4], bff[4];
    #pragma unroll
    for (int i = 0; i < 4; i++)
      af[i] = *(const short8*)&As2[kq][wr * 64 + i * 16 + lr][0];
    #pragma unroll
    for (int j = 0; j < 4; j++)
      bff[j] = *(const short8*)&Bs2[kq][wc * 64 + j * 16 + lr][0];
    #pragma unroll
    for (int i = 0; i < 4; i++)
      #pragma unroll
      for (int j = 0; j < 4; j++)
        acc[i][j] = __builtin_amdgcn_mfma_f32_16x16x32_bf16(
            af[i], bff[j], acc[i][j], 0, 0, 0);
    __syncthreads();
  }

  // epilogue: D layout col=lane&15, row=(lane>>4)*4+r (verified mapping)
  float scl = 0.f;
  int fx = 0, fbias = *fbp;
  if (MODE == 4) { scl = ldin(scalev, 0, *fsp); fx = *fxp; }
  int row0 = bm + wr * 64 + kq * 4;
  int col0 = bn + wc * 64 + lr;
  #pragma unroll
  for (int j = 0; j < 4; j++) {
    int n = col0 + j * 16;
    float bb = ldin(biasv, n, fbias);
    #pragma unroll
    for (int i = 0; i < 4; i++) {
      #pragma unroll
      for (int r = 0; r < 4; r++) {
        int m = row0 + i * 16 + r;
        float v = acc[i][j][r] + bb;
        size_t o = obase + (size_t)m * N + n;
        if (MODE == 2) {
          ((bf16*)O)[o] = __float2bfloat16(gelu_f(v));
        } else if (MODE == 3) {
          ((bf16*)O)[o] = __float2bfloat16(v);
        } else {
          float base = ldin(xinv, o, fx);
          ((float*)O)[o] = base + scl * v;
        }
      }
    }
  }
}

// ---------------- region-mean of s1 bits + qr/kr projection (fp32 weights: routing exact) ----
__global__ void srqkr_k(const u64* __restrict__ bits,
                        const void* __restrict__ Wqkv, const int* __restrict__ fWp,
                        const void* __restrict__ bqkv, const int* __restrict__ fbp,
                        float* __restrict__ qr, float* __restrict__ kr) {
  int fW = *fWp, fb = *fbp;
  int blk = blockIdx.x;   // (t*8+b)*16 + r, 512 regions
  int c = threadIdx.x;    // 256
  __shared__ float s_s[256];
  float s = 0.f;
  for (int i = 0; i < 64; i++) {
    int g = blk * 64 + i;                       // global token
    u64 w = bits[(size_t)g * 4 + (c >> 6)];
    s += (float)((w >> (c & 63)) & 1ull);
  }
  s_s[c] = s * (1.0f / 64.0f);
  __syncthreads();
  float aq = 0.f, ak = 0.f;
  for (int k = 0; k < 256; k++) {
    float sv = s_s[k];
    aq += sv * ldin(Wqkv, (size_t)k * 768 + c, fW);
    ak += sv * ldin(Wqkv, (size_t)k * 768 + 256 + c, fW);
  }
  qr[(size_t)blk * DIM + c] = aq + ldin(bqkv, c, fb);
  kr[(size_t)blk * DIM + c] = ak + ldin(bqkv, 256 + c, fb);
}

// ---------------- affinity + top-4 (ties -> lowest index, matches lax.top_k) ----------------
__global__ void afftopk_k(const float* __restrict__ qr, const float* __restrict__ kr,
                          int* __restrict__ idx) {
  int blk = blockIdx.x;       // (t*8+b)*16 + r
  int tb = blk >> 4;
  int tid = threadIdx.x;      // 256
  int s_ = tid >> 4, p = tid & 15;
  __shared__ float part[256];
  __shared__ float aff[16];
  const float* qrow = qr + (size_t)blk * 256;
  const float* krow = kr + (size_t)(tb * 16 + s_) * 256;
  float acc = 0.f;
  for (int c = p * 16; c < p * 16 + 16; c++) acc += qrow[c] * krow[c];
  part[tid] = acc;
  __syncthreads();
  if (tid < 16) {
    float a = 0.f;
    for (int pp = 0; pp < 16; pp++) a += part[tid * 16 + pp];
    aff[tid] = a;
  }
  __syncthreads();
  if (tid == 0) {
    bool taken[16] = {};
    for (int kk = 0; kk < 4; kk++) {
      float best = -INFINITY; int bi = 0;
      for (int i = 0; i < 16; i++)
        if (!taken[i] && aff[i] > best) { best = aff[i]; bi = i; }
      taken[bi] = true;
      idx[blk * 4 + kk] = bi;
    }
  }
}

// ---------------- gathered attention per (b_local, r, h) within a chunk ----------------
__global__ void __launch_bounds__(256)
attn_k(const bf16* __restrict__ qkv, const int* __restrict__ idx,
       bf16* __restrict__ ctx) {
  __shared__ __align__(16) float qs[64 * 32];     // 8 KB
  __shared__ __align__(16) float sc[256 * 36];    // 36 KB (half the i-rows at a time)
  __shared__ int ridxs[4];
  int blk = blockIdx.x;             // (b_local*16+r)*8 + h
  int h = blk & 7, br = blk >> 3;
  int b = br >> 4;                  // chunk-local batch
  int tid = threadIdx.x;
  if (tid < 4) ridxs[tid] = idx[br * 4 + tid];
  int base = br * 64;               // chunk-local token base
  for (int e = tid; e < 2048; e += 256) {
    int i = e >> 5, d = e & 31;
    qs[i * 32 + d] = __bfloat162float(qkv[(size_t)(base + i) * 768 + h * 32 + d]);
  }
  __syncthreads();

  int j = tid;
  int ktok = b * 1024 + ridxs[j >> 6] * 64 + (j & 63);
  const bf16* krow = qkv + (size_t)ktok * 768 + 256 + h * 32;
  float kreg[32];
  #pragma unroll
  for (int d2 = 0; d2 < 32; d2++) kreg[d2] = __bfloat162float(krow[d2]);

  int d = tid & 31, ig = tid >> 5;
  for (int half = 0; half < 2; half++) {
    for (int i2 = 0; i2 < 32; i2++) {
      int i = half * 32 + i2;
      const float4* q4p = (const float4*)&qs[i * 32];
      float acc = 0.f;
      #pragma unroll
      for (int q4 = 0; q4 < 8; q4++) {
        float4 ff = q4p[q4];
        acc += ff.x * kreg[4*q4] + ff.y * kreg[4*q4+1] + ff.z * kreg[4*q4+2] + ff.w * kreg[4*q4+3];
      }
      sc[j * 36 + i2] = acc * 0.17677669529663687f;   // 1/sqrt(32)
    }
    __syncthreads();
    if (tid < 32) {                                   // serial softmax per query row
      int i2 = tid;
      float mx = -INFINITY;
      for (int jj = 0; jj < 256; jj++) mx = fmaxf(mx, sc[jj * 36 + i2]);
      float sum = 0.f;
      for (int jj = 0; jj < 256; jj++) {
        float e = expf(sc[jj * 36 + i2] - mx);
        sc[jj * 36 + i2] = e; sum += e;
      }
      float inv = 1.0f / sum;
      for (int jj = 0; jj < 256; jj++) sc[jj * 36 + i2] *= inv;
    }
    __syncthreads();
    float acc4[4] = {0.f, 0.f, 0.f, 0.f};
    for (int jj = 0; jj < 256; jj++) {
      int vt = b * 1024 + ridxs[jj >> 6] * 64 + (jj & 63);
      float vv = __bfloat162float(qkv[(size_t)vt * 768 + 512 + h * 32 + d]);
      float4 p4 = *(const float4*)&sc[jj * 36 + ig * 4];
      acc4[0] += p4.x * vv; acc4[1] += p4.y * vv;
      acc4[2] += p4.z * vv; acc4[3] += p4.w * vv;
    }
    #pragma unroll
    for (int ii = 0; ii < 4; ii++) {
      int i = half * 32 + ig * 4 + ii;
      ctx[(size_t)(base + i) * 256 + h * 32 + d] = __float2bfloat16(acc4[ii]);
    }
    __syncthreads();
  }
}

// ---------------- launch ----------------
extern "C" void kernel_launch(void* const* d_in, const int* in_sizes, int n_in,
                              void* d_out, int out_size, void* d_ws, size_t ws_size,
                              hipStream_t stream) {
  const void* x_in = d_in[0];
  const void* Wqkv = d_in[3];
  const void* bqkv = d_in[4];
  const void* Wo   = d_in[5];
  const void* bo   = d_in[6];
  const void* W1   = d_in[9];
  const void* b1   = d_in[10];
  const void* W2   = d_in[11];
  const void* b2   = d_in[12];
  const void* scale = d_in[13];

  // misc: flags(256B) + qr/kr(1MB) + idx(8KB) + bits(1MB) + gsum/gsq(2KB)
  //       + bf16-transposed weights (1.5MB)
  const size_t MISC = 256 + 2 * 524288 + 8192 + 1048576 + 2048 + 1572864;
  int bcq, TC;
  if (MISC + 8388608 <= ws_size) { bcq = 4; TC = 4096; }   // ~12.1 MB
  else                           { bcq = 1; TC = 1024; }   // ~5.8 MB
  size_t r0 = (size_t)bcq * 2097152;   // qkvb (bcq*1.5MB) + ctxb (bcq*0.5MB)
  { size_t hb = (size_t)TC * 2048; if (hb > r0) r0 = hb; }

  char* ws = (char*)d_ws;
  int*  flags = (int*)ws;      // [0..13] per-input dtype; [14]=0 (bf16); [15]=1 (fp32)
  char* p = ws + 256;
  bf16* qkvb = (bf16*)p;
  bf16* ctxb = (bf16*)(p + (size_t)bcq * 1572864);
  bf16* hbuf = (bf16*)p;               // aliases qkvb/ctxb (disjoint phases)
  p += r0;
  float* qr   = (float*)p;  p += 524288;
  float* kr   = (float*)p;  p += 524288;
  int*   idxb = (int*)p;    p += 8192;
  u64*   bits = (u64*)p;    p += 1048576;   // s1 bits, later s2 bits
  float* gsum = (float*)p;  p += 2048;
  float* gsq  = gsum + 256;
  bf16* wqkvt = (bf16*)p;   p += 393216;    // [768][256]
  bf16* wot   = (bf16*)p;   p += 131072;    // [256][256]
  bf16* w1t   = (bf16*)p;   p += 524288;    // [1024][256]
  bf16* w2t   = (bf16*)p;   p += 524288;    // [256][1024]
  float* out  = (float*)d_out;         // FP32 output: x_mid, then final (in place)
  const int* F14 = flags + 14;         // const bf16 flag (0)
  const int* F15 = flags + 15;         // const fp32 flag (1)

  // ---- dtype probes ----
  hipMemsetAsync(flags, 0, 256, stream);
  setone_k<<<1, 1, 0, stream>>>(flags + 15);
  for (int i = 0; i < 14; i++)
    probe1_k<<<1, 64, 0, stream>>>(d_in[i], in_sizes[i], flags + i);

  // ---- one-time weight transpose to bf16 [N][K] for MFMA B operands ----
  wconv_k<<<dim3(1, 768),  256, 0, stream>>>(Wqkv, flags + 3,  wqkvt, 256, 768);
  wconv_k<<<dim3(1, 256),  256, 0, stream>>>(Wo,   flags + 5,  wot,   256, 256);
  wconv_k<<<dim3(1, 1024), 256, 0, stream>>>(W1,   flags + 9,  w1t,   256, 1024);
  wconv_k<<<dim3(4, 256),  256, 0, stream>>>(W2,   flags + 11, w2t,  1024, 256);

  // ---- block 1: BN1 + LIF -> s1 bits ----
  hipMemsetAsync(gsum, 0, 512 * sizeof(float), stream);
  bnstats_k<<<256, 256, 0, stream>>>(x_in, flags + 0, gsum, gsq);
  lif_k<<<MT / 256, 256, 0, stream>>>(x_in, flags + 0, gsum, gsq,
                                      d_in[1], flags + 1, d_in[2], flags + 2, bits);

  // ---- region routing (fp32 weights: exact top-k indices) ----
  srqkr_k<<<512, 256, 0, stream>>>(bits, Wqkv, flags + 3, bqkv, flags + 4, qr, kr);
  afftopk_k<<<512, 256, 0, stream>>>(qr, kr, idxb);

  // ---- attention chunks: s1 bits -> qkv -> attn -> x_mid = x + scale*(ctx@Wo+bo) ----
  for (int t = 0; t < LTT; t++) {
    for (int b0 = 0; b0 < 8; b0 += bcq) {
      size_t tok0 = ((size_t)t * 8 + b0) * 1024;
      mgemm_k<3, 2><<<dim3(6, bcq * 8), 256, 0, stream>>>(
          (const void*)((const u32*)bits + tok0 * 8), wqkvt,
          bqkv, flags + 4, qkvb, nullptr, F14, nullptr, F14, 768, 256, 0);
      attn_k<<<bcq * 128, 256, 0, stream>>>(qkvb, idxb + (t * 8 + b0) * 64, ctxb);
      mgemm_k<4, 0><<<dim3(2, bcq * 8), 256, 0, stream>>>(
          ctxb, wot, bo, flags + 6, out, x_in, flags + 0,
          scale, flags + 13, 256, 256, tok0 * 256);
    }
  }

  // ---- block 2: BN2 + LIF on x_mid (fp32, in d_out) -> s2 bits ----
  hipMemsetAsync(gsum, 0, 512 * sizeof(float), stream);
  bnstats_k<<<256, 256, 0, stream>>>(out, F15, gsum, gsq);
  lif_k<<<MT / 256, 256, 0, stream>>>(out, F15, gsum, gsq,
                                      d_in[7], flags + 7, d_in[8], flags + 8, bits);

  // ---- FFN chunks: s2 bits -> gelu hidden -> out = x_mid + scale*(h@W2+b2) in place ----
  for (int c = 0; c * TC < NTOK; c++) {
    size_t tok0 = (size_t)c * TC;
    mgemm_k<2, 2><<<dim3(8, TC / 128), 256, 0, stream>>>(
        (const void*)((const u32*)bits + tok0 * 8), w1t,
        b1, flags + 10, hbuf, nullptr, F14, nullptr, F14, 1024, 256, 0);
    mgemm_k<4, 0><<<dim3(2, TC / 128), 256, 0, stream>>>(
        hbuf, w2t, b2, flags + 12, out, out, F15,
        scale, flags + 13, 256, 1024, tok0 * 256);
  }
}

// Round 2
// 1176.717 us; speedup vs baseline: 2.7236x; 1.6809x over previous
//
#include <hip/hip_runtime.h>
#include <hip/hip_bf16.h>
#include <math.h>

typedef __hip_bfloat16 bf16;
typedef unsigned long long u64;
typedef unsigned int u32;

#define LTT 4
#define DIM 256
#define NTOK 32768      // total tokens (4*8*1024)
#define MT 2097152      // elements per time step (8192 tokens * 256)
#define NTOT 8388608

typedef __attribute__((ext_vector_type(8))) short short8;   // 8 bf16 (4 VGPRs)
typedef __attribute__((ext_vector_type(4))) float f32x4;

// dual-dtype load with finite clamp: f=1 -> fp32, f=0 -> bf16
__device__ __forceinline__ float ldin(const void* p, size_t i, int f) {
  float v = f ? ((const float*)p)[i] : __bfloat162float(((const bf16*)p)[i]);
  return isfinite(v) ? v : 0.0f;
}

__device__ __forceinline__ short bf16bits(float x) {
  union { bf16 b; short s; } u; u.b = __float2bfloat16(x); return u.s;
}

// ---------------- per-input dtype probe ----------------
__global__ void probe1_k(const void* p, int nelem, int* flag) {
  int tid = threadIdx.x;  // 64
  const unsigned short* u = (const unsigned short*)p;
  int n = nelem < 1024 ? nelem : 1024;
  bool big = false, nz = false;
  for (int i = tid; i < n; i += 64) {
    unsigned short h = u[i];
    if (((h >> 7) & 0xFF) >= 0xC0) big = true;
    if (h != 0) nz = true;
  }
  u64 bm = __ballot(big);
  u64 zm = __ballot(nz);
  if (tid == 0) {
    unsigned short h0 = u[0];
    int f = 0;
    if (bm != 0ull) f = 1;
    else if (h0 == 0 && (zm != 0ull || n == 1)) f = 1;
    *flag = f;
  }
}

__global__ void setone_k(int* p) { *p = 1; }

// ---------------- batchnorm stats: per-channel sums over 32768 tokens ----------------
__global__ void bnstats_k(const void* __restrict__ x, const int* __restrict__ fxp,
                          float* __restrict__ gsum, float* __restrict__ gsq) {
  int fx = *fxp;
  int c = threadIdx.x;            // 256 channels
  int tok0 = blockIdx.x * 128;    // 256 blocks * 128 tokens
  float s = 0.f, q = 0.f;
  for (int t = 0; t < 128; t++) {
    float v = ldin(x, (size_t)(tok0 + t) * DIM + c, fx);
    s += v; q += v * v;
  }
  atomicAdd(&gsum[c], s);
  atomicAdd(&gsq[c], q);
}

// ---------------- fused BN-apply + LIF scan over t; spikes bit-packed ----------------
__global__ void lif_k(const void* __restrict__ x, const int* __restrict__ fxp,
                      const float* __restrict__ gsum, const float* __restrict__ gsq,
                      const void* __restrict__ gamma, const int* __restrict__ fgp,
                      const void* __restrict__ beta, const int* __restrict__ fbp,
                      u64* __restrict__ bits) {
  int fx = *fxp, fg = *fgp, fb = *fbp;
  int m = blockIdx.x * 256 + threadIdx.x;   // [0, MT)
  int c = m & (DIM - 1);
  int lane = threadIdx.x & 63;
  float mean = gsum[c] * (1.0f / 32768.0f);
  float var  = gsq[c] * (1.0f / 32768.0f) - mean * mean;
  float inv  = rsqrtf(var + 1e-5f);
  float g = ldin(gamma, c, fg), be = ldin(beta, c, fb);
  float v = 0.f;
  #pragma unroll
  for (int t = 0; t < LTT; t++) {
    size_t e = (size_t)t * MT + m;
    float xn = (ldin(x, e, fx) - mean) * inv * g + be;
    v = v + (xn - v) * 0.5f;                 // TAU = 2
    bool sp = (v - 1.0f >= 0.0f);            // VTH = 1
    u64 bl = __ballot(sp);
    if (lane == 0) bits[e >> 6] = bl;        // e>>6 is wave-uniform
    v = sp ? 0.0f : v;
  }
}

__device__ __forceinline__ float gelu_f(float x) {
  return 0.5f * x * (1.0f + erff(x * 0.70710678118654752440f));
}

// ---------------- one-time weight convert+transpose: W[K][N] (flag dtype) -> Wt[N][K] bf16 ----
__global__ void wconv_k(const void* __restrict__ W, const int* __restrict__ fp,
                        bf16* __restrict__ Wt, int K, int N) {
  int f = *fp;
  int k = blockIdx.x * 256 + threadIdx.x;
  int n = blockIdx.y;
  Wt[(size_t)n * K + k] = __float2bfloat16(ldin(W, (size_t)k * N + n, f));
}

// ---------------- MFMA bf16 GEMM, 128x128 tile, BK=32, 4 waves ----------------
template <int MODE, int AF>
__global__ void __launch_bounds__(256)
mgemm_k(const void* __restrict__ Av,
        const bf16* __restrict__ Bt,
        const void* __restrict__ biasv, const int* __restrict__ fbp,
        void* O, const void* xinv, const int* __restrict__ fxp,
        const void* __restrict__ scalev, const int* __restrict__ fsp,
        int N, int K, size_t obase) {
  __shared__ __align__(16) short As2[4][128][8];   // 8 KB
  __shared__ __align__(16) short Bs2[4][128][8];   // 8 KB
  const bf16* Ab = (const bf16*)Av;
  const u32* Abits = (const u32*)Av;
  int tid = threadIdx.x;
  int bm = blockIdx.y * 128, bn = blockIdx.x * 128;
  int lane = tid & 63, w = tid >> 6;
  int wr = w >> 1, wc = w & 1;          // wave -> 64x64 quadrant
  int kq = lane >> 4, lr = lane & 15;
  f32x4 acc[4][4] = {};

  for (int k0 = 0; k0 < K; k0 += 32) {
    #pragma unroll
    for (int ch = tid; ch < 512; ch += 256) {
      int m = ch >> 2, kb = ch & 3;
      short8 v;
      if (AF == 2) {
        u32 wb = Abits[(size_t)(bm + m) * (K >> 5) + (k0 >> 5)];
        u32 byte = (wb >> (kb * 8)) & 0xFFu;
        #pragma unroll
        for (int j = 0; j < 8; j++)
          v[j] = (short)(((byte >> j) & 1u) ? 0x3F80 : 0);
      } else {
        v = *(const short8*)&Ab[(size_t)(bm + m) * K + k0 + kb * 8];
      }
      *(short8*)&As2[kb][m][0] = v;
    }
    #pragma unroll
    for (int ch = tid; ch < 512; ch += 256) {
      int n = ch >> 2, kb = ch & 3;
      *(short8*)&Bs2[kb][n][0] =
          *(const short8*)&Bt[(size_t)(bn + n) * K + k0 + kb * 8];
    }
    __syncthreads();

    short8 af[4], bff[4];
    #pragma unroll
    for (int i = 0; i < 4; i++)
      af[i] = *(const short8*)&As2[kq][wr * 64 + i * 16 + lr][0];
    #pragma unroll
    for (int j = 0; j < 4; j++)
      bff[j] = *(const short8*)&Bs2[kq][wc * 64 + j * 16 + lr][0];
    #pragma unroll
    for (int i = 0; i < 4; i++)
      #pragma unroll
      for (int j = 0; j < 4; j++)
        acc[i][j] = __builtin_amdgcn_mfma_f32_16x16x32_bf16(
            af[i], bff[j], acc[i][j], 0, 0, 0);
    __syncthreads();
  }

  float scl = 0.f;
  int fx = 0, fbias = *fbp;
  if (MODE == 4) { scl = ldin(scalev, 0, *fsp); fx = *fxp; }
  int row0 = bm + wr * 64 + kq * 4;
  int col0 = bn + wc * 64 + lr;
  #pragma unroll
  for (int j = 0; j < 4; j++) {
    int n = col0 + j * 16;
    float bb = ldin(biasv, n, fbias);
    #pragma unroll
    for (int i = 0; i < 4; i++) {
      #pragma unroll
      for (int r = 0; r < 4; r++) {
        int m = row0 + i * 16 + r;
        float v = acc[i][j][r] + bb;
        size_t o = obase + (size_t)m * N + n;
        if (MODE == 2) {
          ((bf16*)O)[o] = __float2bfloat16(gelu_f(v));
        } else if (MODE == 3) {
          ((bf16*)O)[o] = __float2bfloat16(v);
        } else {
          float base = ldin(xinv, o, fx);
          ((float*)O)[o] = base + scl * v;
        }
      }
    }
  }
}

// ---------------- region-mean of s1 bits + qr/kr projection (fp32 weights: routing exact) ----
__global__ void srqkr_k(const u64* __restrict__ bits,
                        const void* __restrict__ Wqkv, const int* __restrict__ fWp,
                        const void* __restrict__ bqkv, const int* __restrict__ fbp,
                        float* __restrict__ qr, float* __restrict__ kr) {
  int fW = *fWp, fb = *fbp;
  int blk = blockIdx.x;   // (t*8+b)*16 + r, 512 regions
  int c = threadIdx.x;    // 256
  __shared__ float s_s[256];
  float s = 0.f;
  for (int i = 0; i < 64; i++) {
    int g = blk * 64 + i;                       // global token
    u64 w = bits[(size_t)g * 4 + (c >> 6)];
    s += (float)((w >> (c & 63)) & 1ull);
  }
  s_s[c] = s * (1.0f / 64.0f);
  __syncthreads();
  float aq = 0.f, ak = 0.f;
  for (int k = 0; k < 256; k++) {
    float sv = s_s[k];
    aq += sv * ldin(Wqkv, (size_t)k * 768 + c, fW);
    ak += sv * ldin(Wqkv, (size_t)k * 768 + 256 + c, fW);
  }
  qr[(size_t)blk * DIM + c] = aq + ldin(bqkv, c, fb);
  kr[(size_t)blk * DIM + c] = ak + ldin(bqkv, 256 + c, fb);
}

// ---------------- affinity + top-4 (ties -> lowest index, matches lax.top_k) ----------------
__global__ void afftopk_k(const float* __restrict__ qr, const float* __restrict__ kr,
                          int* __restrict__ idx) {
  int blk = blockIdx.x;       // (t*8+b)*16 + r
  int tb = blk >> 4;
  int tid = threadIdx.x;      // 256
  int s_ = tid >> 4, p = tid & 15;
  __shared__ float part[256];
  __shared__ float aff[16];
  const float* qrow = qr + (size_t)blk * 256;
  const float* krow = kr + (size_t)(tb * 16 + s_) * 256;
  float acc = 0.f;
  for (int c = p * 16; c < p * 16 + 16; c++) acc += qrow[c] * krow[c];
  part[tid] = acc;
  __syncthreads();
  if (tid < 16) {
    float a = 0.f;
    for (int pp = 0; pp < 16; pp++) a += part[tid * 16 + pp];
    aff[tid] = a;
  }
  __syncthreads();
  if (tid == 0) {
    bool taken[16] = {};
    for (int kk = 0; kk < 4; kk++) {
      float best = -INFINITY; int bi = 0;
      for (int i = 0; i < 16; i++)
        if (!taken[i] && aff[i] > best) { best = aff[i]; bi = i; }
      taken[bi] = true;
      idx[blk * 4 + kk] = bi;
    }
  }
}

// ---------------- MFMA gathered attention per (b_local, r, h) ----------------
// 4 waves x 16 query rows. K staged [tok][d] (B-frags = contiguous b128).
// V staged transposed [d][k] with per-row rotation col=(k+8d)&255 (aligned b128,
// full bank spread). S accum in registers (C layout col=lane&15,row=(lane>>4)*4+r);
// wave-parallel softmax (reduce over 16 N-tiles in-lane + shfl_xor 1/2/4/8 across
// the 16-lane row group). P (normalized, bf16) -> LDS with col ^= (row&7)<<3
// swizzle so PV A-frags stay aligned b128. PV: 16 MFMAs/wave.
__global__ void __launch_bounds__(256)
attn_k(const bf16* __restrict__ qkv, const int* __restrict__ idx,
       bf16* __restrict__ ctx) {
  __shared__ __align__(16) short Ks[256][32];     // 16 KB
  __shared__ __align__(16) short Vs[32][256];     // 16 KB (rotated V^T)
  __shared__ __align__(16) short Ps[4][16][256];  // 32 KB (per-wave P, swizzled)
  int blk = blockIdx.x;             // (b_local*16+r)*8 + h
  int h = blk & 7, br = blk >> 3;
  int b = br >> 4;                  // chunk-local batch
  int tid = threadIdx.x;
  int base = br * 64;               // chunk-local token base
  int r0 = idx[br * 4 + 0], r1 = idx[br * 4 + 1];
  int r2 = idx[br * 4 + 2], r3 = idx[br * 4 + 3];

  // ---- stage K: g=(token,chunk) so consecutive lanes -> consecutive 16B ----
  #pragma unroll
  for (int c = 0; c < 4; c++) {
    int g = c * 256 + tid;
    int tk = g >> 2, ch = g & 3;
    int rs = tk >> 6;
    int rid = (rs & 2) ? ((rs & 1) ? r3 : r2) : ((rs & 1) ? r1 : r0);
    int gt = b * 1024 + rid * 64 + (tk & 63);
    short8 v = *(const short8*)&qkv[(size_t)gt * 768 + 256 + h * 32 + ch * 8];
    *(short8*)&Ks[tk][ch * 8] = v;
  }
  // ---- stage V^T rotated: thread tid = token ----
  {
    int tk = tid;
    int rs = tk >> 6;
    int rid = (rs & 2) ? ((rs & 1) ? r3 : r2) : ((rs & 1) ? r1 : r0);
    int gt = b * 1024 + rid * 64 + (tk & 63);
    const bf16* vp = &qkv[(size_t)gt * 768 + 512 + h * 32];
    short vv[32];
    *(short8*)&vv[0]  = *(const short8*)&vp[0];
    *(short8*)&vv[8]  = *(const short8*)&vp[8];
    *(short8*)&vv[16] = *(const short8*)&vp[16];
    *(short8*)&vv[24] = *(const short8*)&vp[24];
    #pragma unroll
    for (int d = 0; d < 32; d++)
      Vs[d][(tk + 8 * d) & 255] = vv[d];
  }
  __syncthreads();

  int w = tid >> 6, lane = tid & 63, kq = lane >> 4, lr = lane & 15;

  // ---- Q fragment straight from global: row = base+w*16+lr, k = kq*8..+7 ----
  short8 qf = *(const short8*)&qkv[(size_t)(base + w * 16 + lr) * 768 + h * 32 + kq * 8];

  // ---- QK^T: 16 N-tiles of 16 keys, K=32 in one MFMA each ----
  f32x4 s[16];
  #pragma unroll
  for (int nt = 0; nt < 16; nt++) {
    short8 kf = *(const short8*)&Ks[nt * 16 + lr][kq * 8];
    f32x4 z = {0.f, 0.f, 0.f, 0.f};
    s[nt] = __builtin_amdgcn_mfma_f32_16x16x32_bf16(qf, kf, z, 0, 0, 0);
  }

  // ---- wave-parallel softmax over 256 keys per row (4 rows/lane) ----
  const float cs = 0.17677669529663687f;   // 1/sqrt(32), folded into exp arg
  float mx[4] = {-INFINITY, -INFINITY, -INFINITY, -INFINITY};
  #pragma unroll
  for (int nt = 0; nt < 16; nt++)
    #pragma unroll
    for (int r = 0; r < 4; r++) mx[r] = fmaxf(mx[r], s[nt][r]);
  #pragma unroll
  for (int m = 1; m < 16; m <<= 1)
    #pragma unroll
    for (int r = 0; r < 4; r++) mx[r] = fmaxf(mx[r], __shfl_xor(mx[r], m, 64));
  float sum[4] = {0.f, 0.f, 0.f, 0.f};
  #pragma unroll
  for (int nt = 0; nt < 16; nt++)
    #pragma unroll
    for (int r = 0; r < 4; r++) {
      float e = __expf((s[nt][r] - mx[r]) * cs);
      s[nt][r] = e; sum[r] += e;
    }
  #pragma unroll
  for (int m = 1; m < 16; m <<= 1)
    #pragma unroll
    for (int r = 0; r < 4; r++) sum[r] += __shfl_xor(sum[r], m, 64);
  float inv[4];
  #pragma unroll
  for (int r = 0; r < 4; r++) inv[r] = 1.0f / sum[r];

  // ---- normalized P -> LDS (bf16), col XOR-swizzled per row ----
  #pragma unroll
  for (int nt = 0; nt < 16; nt++)
    #pragma unroll
    for (int r = 0; r < 4; r++) {
      int row = kq * 4 + r;
      int col = nt * 16 + lr;
      Ps[w][row][col ^ ((row & 7) << 3)] = bf16bits(s[nt][r] * inv[r]);
    }
  __syncthreads();

  // ---- PV: M=16, N=32 (2 tiles), K=256 (8 chunks) ----
  f32x4 o0 = {0.f, 0.f, 0.f, 0.f}, o1 = {0.f, 0.f, 0.f, 0.f};
  #pragma unroll
  for (int kc = 0; kc < 8; kc++) {
    // A-frag: logical P[lr][kc*32+kq*8+j]; apply inverse swizzle for row=lr
    short8 pf = *(const short8*)
        &Ps[w][lr][(kc ^ ((lr >> 2) & 1)) * 32 + (kq ^ (lr & 3)) * 8];
    // B-frags: V^T[d][k] at rotated col (k+8d)&255, d = dt*16+lr
    int d0 = lr, d1 = 16 + lr;
    short8 vf0 = *(const short8*)&Vs[d0][(kc * 32 + kq * 8 + 8 * d0) & 255];
    short8 vf1 = *(const short8*)&Vs[d1][(kc * 32 + kq * 8 + 8 * d1) & 255];
    o0 = __builtin_amdgcn_mfma_f32_16x16x32_bf16(pf, vf0, o0, 0, 0, 0);
    o1 = __builtin_amdgcn_mfma_f32_16x16x32_bf16(pf, vf1, o1, 0, 0, 0);
  }

  // ---- store ctx: row = base+w*16+kq*4+r, col = h*32 + dt*16 + lr ----
  #pragma unroll
  for (int r = 0; r < 4; r++) {
    int q = base + w * 16 + kq * 4 + r;
    ctx[(size_t)q * 256 + h * 32 + lr]      = __float2bfloat16(o0[r]);
    ctx[(size_t)q * 256 + h * 32 + 16 + lr] = __float2bfloat16(o1[r]);
  }
}

// ---------------- launch ----------------
extern "C" void kernel_launch(void* const* d_in, const int* in_sizes, int n_in,
                              void* d_out, int out_size, void* d_ws, size_t ws_size,
                              hipStream_t stream) {
  const void* x_in = d_in[0];
  const void* Wqkv = d_in[3];
  const void* bqkv = d_in[4];
  const void* Wo   = d_in[5];
  const void* bo   = d_in[6];
  const void* W1   = d_in[9];
  const void* b1   = d_in[10];
  const void* W2   = d_in[11];
  const void* b2   = d_in[12];
  const void* scale = d_in[13];

  const size_t MISC = 256 + 2 * 524288 + 8192 + 1048576 + 2048 + 1572864;
  int bcq, TC;
  if (MISC + 8388608 <= ws_size) { bcq = 4; TC = 4096; }
  else                           { bcq = 1; TC = 1024; }
  size_t r0 = (size_t)bcq * 2097152;
  { size_t hb = (size_t)TC * 2048; if (hb > r0) r0 = hb; }

  char* ws = (char*)d_ws;
  int*  flags = (int*)ws;
  char* p = ws + 256;
  bf16* qkvb = (bf16*)p;
  bf16* ctxb = (bf16*)(p + (size_t)bcq * 1572864);
  bf16* hbuf = (bf16*)p;
  p += r0;
  float* qr   = (float*)p;  p += 524288;
  float* kr   = (float*)p;  p += 524288;
  int*   idxb = (int*)p;    p += 8192;
  u64*   bits = (u64*)p;    p += 1048576;
  float* gsum = (float*)p;  p += 2048;
  float* gsq  = gsum + 256;
  bf16* wqkvt = (bf16*)p;   p += 393216;    // [768][256]
  bf16* wot   = (bf16*)p;   p += 131072;    // [256][256]
  bf16* w1t   = (bf16*)p;   p += 524288;    // [1024][256]
  bf16* w2t   = (bf16*)p;   p += 524288;    // [256][1024]
  float* out  = (float*)d_out;
  const int* F14 = flags + 14;
  const int* F15 = flags + 15;

  // ---- dtype probes ----
  hipMemsetAsync(flags, 0, 256, stream);
  setone_k<<<1, 1, 0, stream>>>(flags + 15);
  for (int i = 0; i < 14; i++)
    probe1_k<<<1, 64, 0, stream>>>(d_in[i], in_sizes[i], flags + i);

  // ---- one-time weight transpose to bf16 [N][K] ----
  wconv_k<<<dim3(1, 768),  256, 0, stream>>>(Wqkv, flags + 3,  wqkvt, 256, 768);
  wconv_k<<<dim3(1, 256),  256, 0, stream>>>(Wo,   flags + 5,  wot,   256, 256);
  wconv_k<<<dim3(1, 1024), 256, 0, stream>>>(W1,   flags + 9,  w1t,   256, 1024);
  wconv_k<<<dim3(4, 256),  256, 0, stream>>>(W2,   flags + 11, w2t,  1024, 256);

  // ---- block 1: BN1 + LIF -> s1 bits ----
  hipMemsetAsync(gsum, 0, 512 * sizeof(float), stream);
  bnstats_k<<<256, 256, 0, stream>>>(x_in, flags + 0, gsum, gsq);
  lif_k<<<MT / 256, 256, 0, stream>>>(x_in, flags + 0, gsum, gsq,
                                      d_in[1], flags + 1, d_in[2], flags + 2, bits);

  // ---- region routing (fp32 weights: exact top-k indices) ----
  srqkr_k<<<512, 256, 0, stream>>>(bits, Wqkv, flags + 3, bqkv, flags + 4, qr, kr);
  afftopk_k<<<512, 256, 0, stream>>>(qr, kr, idxb);

  // ---- attention chunks ----
  for (int t = 0; t < LTT; t++) {
    for (int b0 = 0; b0 < 8; b0 += bcq) {
      size_t tok0 = ((size_t)t * 8 + b0) * 1024;
      mgemm_k<3, 2><<<dim3(6, bcq * 8), 256, 0, stream>>>(
          (const void*)((const u32*)bits + tok0 * 8), wqkvt,
          bqkv, flags + 4, qkvb, nullptr, F14, nullptr, F14, 768, 256, 0);
      attn_k<<<bcq * 128, 256, 0, stream>>>(qkvb, idxb + (t * 8 + b0) * 64, ctxb);
      mgemm_k<4, 0><<<dim3(2, bcq * 8), 256, 0, stream>>>(
          ctxb, wot, bo, flags + 6, out, x_in, flags + 0,
          scale, flags + 13, 256, 256, tok0 * 256);
    }
  }

  // ---- block 2: BN2 + LIF on x_mid ----
  hipMemsetAsync(gsum, 0, 512 * sizeof(float), stream);
  bnstats_k<<<256, 256, 0, stream>>>(out, F15, gsum, gsq);
  lif_k<<<MT / 256, 256, 0, stream>>>(out, F15, gsum, gsq,
                                      d_in[7], flags + 7, d_in[8], flags + 8, bits);

  // ---- FFN chunks ----
  for (int c = 0; c * TC < NTOK; c++) {
    size_t tok0 = (size_t)c * TC;
    mgemm_k<2, 2><<<dim3(8, TC / 128), 256, 0, stream>>>(
        (const void*)((const u32*)bits + tok0 * 8), w1t,
        b1, flags + 10, hbuf, nullptr, F14, nullptr, F14, 1024, 256, 0);
    mgemm_k<4, 0><<<dim3(2, TC / 128), 256, 0, stream>>>(
        hbuf, w2t, b2, flags + 12, out, out, F15,
        scale, flags + 13, 256, 1024, tok0 * 256);
  }
}

// Round 3
// 717.576 us; speedup vs baseline: 4.4663x; 1.6399x over previous
//
#include <hip/hip_runtime.h>
#include <hip/hip_bf16.h>
#include <math.h>

typedef __hip_bfloat16 bf16;
typedef unsigned long long u64;
typedef unsigned int u32;

#define LTT 4
#define DIM 256
#define NTOK 32768      // total tokens (4*8*1024)
#define MT 2097152      // elements per time step (8192 tokens * 256)
#define NTOT 8388608

typedef __attribute__((ext_vector_type(8))) short short8;   // 8 bf16 (4 VGPRs)
typedef __attribute__((ext_vector_type(4))) float f32x4;
typedef __attribute__((ext_vector_type(4))) u32 u32x4;

// dual-dtype load with finite clamp: f=1 -> fp32, f=0 -> bf16
__device__ __forceinline__ float ldin(const void* p, size_t i, int f) {
  float v = f ? ((const float*)p)[i] : __bfloat162float(((const bf16*)p)[i]);
  return isfinite(v) ? v : 0.0f;
}

__device__ __forceinline__ short bf16bits(float x) {
  union { bf16 b; short s; } u; u.b = __float2bfloat16(x); return u.s;
}

// ---------------- per-input dtype probes, all inputs in one launch ----------------
struct PtrPack { const void* p[14]; int n[14]; };

__global__ void probe_all_k(PtrPack pk, int* flags) {
  int b = blockIdx.x;            // 14 blocks, one per input
  int tid = threadIdx.x;         // 64
  const unsigned short* u = (const unsigned short*)pk.p[b];
  int nelem = pk.n[b];
  int n = nelem < 1024 ? nelem : 1024;
  bool big = false, nz = false;
  for (int i = tid; i < n; i += 64) {
    unsigned short h = u[i];
    if (((h >> 7) & 0xFF) >= 0xC0) big = true;
    if (h != 0) nz = true;
  }
  u64 bm = __ballot(big);
  u64 zm = __ballot(nz);
  if (tid == 0) {
    unsigned short h0 = u[0];
    int f = 0;
    if (bm != 0ull) f = 1;
    else if (h0 == 0 && (zm != 0ull || n == 1)) f = 1;
    flags[b] = f;
    if (b == 0) flags[15] = 1;   // const fp32 flag
  }
}

// ---------------- batchnorm stats: per-channel sums over 32768 tokens ----------------
__global__ void bnstats_k(const void* __restrict__ x, const int* __restrict__ fxp,
                          float* __restrict__ gsum, float* __restrict__ gsq) {
  int fx = *fxp;
  int c = threadIdx.x;            // 256 channels
  int tok0 = blockIdx.x * 128;    // 256 blocks * 128 tokens
  float s = 0.f, q = 0.f;
  for (int t = 0; t < 128; t++) {
    float v = ldin(x, (size_t)(tok0 + t) * DIM + c, fx);
    s += v; q += v * v;
  }
  atomicAdd(&gsum[c], s);
  atomicAdd(&gsq[c], q);
}

// ---------------- fused BN-apply + LIF scan over t; spikes bit-packed ----------------
__global__ void lif_k(const void* __restrict__ x, const int* __restrict__ fxp,
                      const float* __restrict__ gsum, const float* __restrict__ gsq,
                      const void* __restrict__ gamma, const int* __restrict__ fgp,
                      const void* __restrict__ beta, const int* __restrict__ fbp,
                      u64* __restrict__ bits) {
  int fx = *fxp, fg = *fgp, fb = *fbp;
  int m = blockIdx.x * 256 + threadIdx.x;   // [0, MT)
  int c = m & (DIM - 1);
  int lane = threadIdx.x & 63;
  float mean = gsum[c] * (1.0f / 32768.0f);
  float var  = gsq[c] * (1.0f / 32768.0f) - mean * mean;
  float inv  = rsqrtf(var + 1e-5f);
  float g = ldin(gamma, c, fg), be = ldin(beta, c, fb);
  float v = 0.f;
  #pragma unroll
  for (int t = 0; t < LTT; t++) {
    size_t e = (size_t)t * MT + m;
    float xn = (ldin(x, e, fx) - mean) * inv * g + be;
    v = v + (xn - v) * 0.5f;                 // TAU = 2
    bool sp = (v - 1.0f >= 0.0f);            // VTH = 1
    u64 bl = __ballot(sp);
    if (lane == 0) bits[e >> 6] = bl;        // e>>6 is wave-uniform
    v = sp ? 0.0f : v;
  }
}

__device__ __forceinline__ float gelu_f(float x) {
  return 0.5f * x * (1.0f + erff(x * 0.70710678118654752440f));
}

// ---------------- one-time weight convert+transpose (all 4 weights, one launch) ----
// W[K][N] (flag dtype) -> Wt[N][K] bf16
__global__ void wconv_all_k(const void* __restrict__ Wqkv, const void* __restrict__ Wo,
                            const void* __restrict__ W1, const void* __restrict__ W2,
                            const int* __restrict__ flags,
                            bf16* __restrict__ wqkvt, bf16* __restrict__ wot,
                            bf16* __restrict__ w1t, bf16* __restrict__ w2t) {
  int b = blockIdx.x, t = threadIdx.x;
  const void* W; const int* f; bf16* o; int K, N, n, kblk = 0;
  if (b < 768)       { W = Wqkv; f = flags + 3;  o = wqkvt; K = 256;  N = 768;  n = b; }
  else if (b < 1024) { W = Wo;   f = flags + 5;  o = wot;   K = 256;  N = 256;  n = b - 768; }
  else if (b < 2048) { W = W1;   f = flags + 9;  o = w1t;   K = 256;  N = 1024; n = b - 1024; }
  else { W = W2; f = flags + 11; o = w2t; K = 1024; N = 256;
         int q = b - 2048; kblk = q >> 8; n = q & 255; }
  int k = kblk * 256 + t;
  o[(size_t)n * K + k] = __float2bfloat16(ldin(W, (size_t)k * N + n, *f));
}

// ---------------- LDS-free direct MFMA GEMM, 128x128 tile, 4 waves ----------------
// B: Bt = transposed bf16 [N][K], L2-resident weights; B-frags read directly from
// global (lane pattern: 16 rows x 64B contiguous = 16 full lines -> optimal).
// ABITS=1: A is bit-packed spikes (8 u32/row, K=256 fixed); each lane preloads its
//          4 rows' bit words into VGPRs; byte->8 bf16 via 4KB LDS LUT (1 ds_read_b128).
// ABITS=0: A is bf16 [M][K]; A-frags read directly from global (same line pattern).
// MODE 2: O(bf16) = gelu(acc+bias)
// MODE 3: O(bf16) = acc+bias
// MODE 4: Of32[obase+o] = xin[obase+o] + scl*(acc+bias)  (FFN2 aliases O==xin,
//         same element same thread -> O/xinv NOT __restrict__)
template <int MODE, int ABITS>
__global__ void __launch_bounds__(256)
dgemm_k(const void* __restrict__ Av, const bf16* __restrict__ Bt,
        const void* __restrict__ biasv, const int* __restrict__ fbp,
        void* O, const void* xinv, const int* __restrict__ fxp,
        const void* __restrict__ scalev, const int* __restrict__ fsp,
        int N, int K, size_t obase) {
  int tid = threadIdx.x;
  int lane = tid & 63, w = tid >> 6;
  int wr = w >> 1, wc = w & 1;          // wave -> 64x64 quadrant
  int kq = lane >> 4, lr = lane & 15;
  int bm = blockIdx.y * 128, bn = blockIdx.x * 128;
  f32x4 acc[4][4] = {};

  if constexpr (ABITS) {
    // K = 256 fixed for spike GEMMs.
    __shared__ __align__(16) short lut[256][8];
    {
      short8 e;
      #pragma unroll
      for (int j = 0; j < 8; j++) e[j] = ((tid >> j) & 1) ? (short)0x3F80 : (short)0;
      *(short8*)&lut[tid][0] = e;
    }
    const u32* Abits = (const u32*)Av;
    u32 ab[4][8];
    #pragma unroll
    for (int i = 0; i < 4; i++) {
      const u32* rp = &Abits[(size_t)(bm + wr * 64 + i * 16 + lr) * 8];
      *(u32x4*)&ab[i][0] = *(const u32x4*)&rp[0];
      *(u32x4*)&ab[i][4] = *(const u32x4*)&rp[4];
    }
    __syncthreads();
    #pragma unroll
    for (int s = 0; s < 8; s++) {        // k0 = s*32
      short8 af[4], bf[4];
      #pragma unroll
      for (int i = 0; i < 4; i++) {
        u32 byte = (ab[i][s] >> (kq * 8)) & 0xFFu;
        af[i] = *(const short8*)&lut[byte][0];
      }
      #pragma unroll
      for (int j = 0; j < 4; j++)
        bf[j] = *(const short8*)&Bt[(size_t)(bn + wc * 64 + j * 16 + lr) * 256 + s * 32 + kq * 8];
      #pragma unroll
      for (int i = 0; i < 4; i++)
        #pragma unroll
        for (int j = 0; j < 4; j++)
          acc[i][j] = __builtin_amdgcn_mfma_f32_16x16x32_bf16(af[i], bf[j], acc[i][j], 0, 0, 0);
    }
  } else {
    const bf16* Ab = (const bf16*)Av;
    for (int k0 = 0; k0 < K; k0 += 32) {
      short8 af[4], bf[4];
      #pragma unroll
      for (int i = 0; i < 4; i++)
        af[i] = *(const short8*)&Ab[(size_t)(bm + wr * 64 + i * 16 + lr) * K + k0 + kq * 8];
      #pragma unroll
      for (int j = 0; j < 4; j++)
        bf[j] = *(const short8*)&Bt[(size_t)(bn + wc * 64 + j * 16 + lr) * K + k0 + kq * 8];
      #pragma unroll
      for (int i = 0; i < 4; i++)
        #pragma unroll
        for (int j = 0; j < 4; j++)
          acc[i][j] = __builtin_amdgcn_mfma_f32_16x16x32_bf16(af[i], bf[j], acc[i][j], 0, 0, 0);
    }
  }

  // epilogue: D layout col=lane&15, row=(lane>>4)*4+r (verified mapping)
  float scl = 0.f;
  int fx = 0, fbias = *fbp;
  if (MODE == 4) { scl = ldin(scalev, 0, *fsp); fx = *fxp; }
  int row0 = bm + wr * 64 + kq * 4;
  int col0 = bn + wc * 64 + lr;
  #pragma unroll
  for (int j = 0; j < 4; j++) {
    int n = col0 + j * 16;
    float bb = ldin(biasv, n, fbias);
    #pragma unroll
    for (int i = 0; i < 4; i++) {
      #pragma unroll
      for (int r = 0; r < 4; r++) {
        int m = row0 + i * 16 + r;
        float v = acc[i][j][r] + bb;
        size_t o = obase + (size_t)m * N + n;
        if (MODE == 2) {
          ((bf16*)O)[o] = __float2bfloat16(gelu_f(v));
        } else if (MODE == 3) {
          ((bf16*)O)[o] = __float2bfloat16(v);
        } else {
          float base = ldin(xinv, o, fx);
          ((float*)O)[o] = base + scl * v;
        }
      }
    }
  }
}

// ---------------- region-mean of spike bits: sreg[512][256] fp32 ----------------
__global__ void regmean_k(const u64* __restrict__ bits, float* __restrict__ sreg) {
  int blk = blockIdx.x;   // 512 regions
  int c = threadIdx.x;    // 256
  float s = 0.f;
  for (int i = 0; i < 64; i++) {
    u64 w = bits[(size_t)(blk * 64 + i) * 4 + (c >> 6)];
    s += (float)((w >> (c & 63)) & 1ull);
  }
  sreg[(size_t)blk * 256 + c] = s * (1.0f / 64.0f);
}

// ---------------- routing projection: qkr[512][512] = sreg @ Wqkv[:, :512] + bqkv ----
// fp32 tiled GEMM (exact routing, matches lax.top_k on fp32 affinities).
__global__ void __launch_bounds__(256)
pgemm_k(const float* __restrict__ A,          // sreg [512][256]
        const void* __restrict__ Bv, const int* __restrict__ fBp,   // Wqkv, row stride 768
        const void* __restrict__ biasv, const int* __restrict__ fbp,
        float* __restrict__ Oq) {             // qkr [512][512]
  int fB = *fBp, fb = *fbp;
  __shared__ float Ast[16][68];
  __shared__ float Bs[16][68];
  int tid = threadIdx.x;
  int bm = blockIdx.y * 64, bn = blockIdx.x * 64;
  int tr = tid >> 4, tc = tid & 15;
  float acc[4][4] = {};
  for (int k0 = 0; k0 < 256; k0 += 16) {
    for (int t = tid; t < 1024; t += 256) {
      int m = t >> 4, k = t & 15;
      Ast[k][m] = A[(size_t)(bm + m) * 256 + k0 + k];
    }
    for (int t = tid; t < 1024; t += 256) {
      int k = t >> 6, n = t & 63;
      Bs[k][n] = ldin(Bv, (size_t)(k0 + k) * 768 + bn + n, fB);
    }
    __syncthreads();
    #pragma unroll
    for (int kk = 0; kk < 16; kk++) {
      float4 a4 = *(const float4*)&Ast[kk][tr * 4];
      float4 b4 = *(const float4*)&Bs[kk][tc * 4];
      float a[4] = {a4.x, a4.y, a4.z, a4.w};
      float b[4] = {b4.x, b4.y, b4.z, b4.w};
      #pragma unroll
      for (int i = 0; i < 4; i++)
        #pragma unroll
        for (int jj = 0; jj < 4; jj++)
          acc[i][jj] += a[i] * b[jj];
    }
    __syncthreads();
  }
  #pragma unroll
  for (int i = 0; i < 4; i++)
    #pragma unroll
    for (int jj = 0; jj < 4; jj++) {
      int n = bn + tc * 4 + jj;
      Oq[(size_t)(bm + tr * 4 + i) * 512 + n] = acc[i][jj] + ldin(biasv, n, fb);
    }
}

// ---------------- affinity + top-4 (ties -> lowest index, matches lax.top_k) ----------------
__global__ void afftopk_k(const float* __restrict__ qkr, int* __restrict__ idx) {
  int blk = blockIdx.x;       // (t*8+b)*16 + r
  int tb = blk >> 4;
  int tid = threadIdx.x;      // 256
  int s_ = tid >> 4, p = tid & 15;
  __shared__ float part[256];
  __shared__ float aff[16];
  const float* qrow = qkr + (size_t)blk * 512;                 // q half
  const float* krow = qkr + (size_t)(tb * 16 + s_) * 512 + 256; // k half
  float acc = 0.f;
  for (int c = p * 16; c < p * 16 + 16; c++) acc += qrow[c] * krow[c];
  part[tid] = acc;
  __syncthreads();
  if (tid < 16) {
    float a = 0.f;
    for (int pp = 0; pp < 16; pp++) a += part[tid * 16 + pp];
    aff[tid] = a;
  }
  __syncthreads();
  if (tid == 0) {
    bool taken[16] = {};
    for (int kk = 0; kk < 4; kk++) {
      float best = -INFINITY; int bi = 0;
      for (int i = 0; i < 16; i++)
        if (!taken[i] && aff[i] > best) { best = aff[i]; bi = i; }
      taken[bi] = true;
      idx[blk * 4 + kk] = bi;
    }
  }
}

// ---------------- MFMA gathered attention per (b_local, r, h) ----------------
__global__ void __launch_bounds__(256)
attn_k(const bf16* __restrict__ qkv, const int* __restrict__ idx,
       bf16* __restrict__ ctx) {
  __shared__ __align__(16) short Ks[256][32];     // 16 KB
  __shared__ __align__(16) short Vs[32][256];     // 16 KB (rotated V^T)
  __shared__ __align__(16) short Ps[4][16][256];  // 32 KB (per-wave P, swizzled)
  int blk = blockIdx.x;             // (b_local*16+r)*8 + h
  int h = blk & 7, br = blk >> 3;
  int b = br >> 4;                  // chunk-local batch
  int tid = threadIdx.x;
  int base = br * 64;               // chunk-local token base
  int r0 = idx[br * 4 + 0], r1 = idx[br * 4 + 1];
  int r2 = idx[br * 4 + 2], r3 = idx[br * 4 + 3];

  #pragma unroll
  for (int c = 0; c < 4; c++) {
    int g = c * 256 + tid;
    int tk = g >> 2, ch = g & 3;
    int rs = tk >> 6;
    int rid = (rs & 2) ? ((rs & 1) ? r3 : r2) : ((rs & 1) ? r1 : r0);
    int gt = b * 1024 + rid * 64 + (tk & 63);
    short8 v = *(const short8*)&qkv[(size_t)gt * 768 + 256 + h * 32 + ch * 8];
    *(short8*)&Ks[tk][ch * 8] = v;
  }
  {
    int tk = tid;
    int rs = tk >> 6;
    int rid = (rs & 2) ? ((rs & 1) ? r3 : r2) : ((rs & 1) ? r1 : r0);
    int gt = b * 1024 + rid * 64 + (tk & 63);
    const bf16* vp = &qkv[(size_t)gt * 768 + 512 + h * 32];
    short vv[32];
    *(short8*)&vv[0]  = *(const short8*)&vp[0];
    *(short8*)&vv[8]  = *(const short8*)&vp[8];
    *(short8*)&vv[16] = *(const short8*)&vp[16];
    *(short8*)&vv[24] = *(const short8*)&vp[24];
    #pragma unroll
    for (int d = 0; d < 32; d++)
      Vs[d][(tk + 8 * d) & 255] = vv[d];
  }
  __syncthreads();

  int w = tid >> 6, lane = tid & 63, kq = lane >> 4, lr = lane & 15;

  short8 qf = *(const short8*)&qkv[(size_t)(base + w * 16 + lr) * 768 + h * 32 + kq * 8];

  f32x4 s[16];
  #pragma unroll
  for (int nt = 0; nt < 16; nt++) {
    short8 kf = *(const short8*)&Ks[nt * 16 + lr][kq * 8];
    f32x4 z = {0.f, 0.f, 0.f, 0.f};
    s[nt] = __builtin_amdgcn_mfma_f32_16x16x32_bf16(qf, kf, z, 0, 0, 0);
  }

  const float cs = 0.17677669529663687f;   // 1/sqrt(32)
  float mx[4] = {-INFINITY, -INFINITY, -INFINITY, -INFINITY};
  #pragma unroll
  for (int nt = 0; nt < 16; nt++)
    #pragma unroll
    for (int r = 0; r < 4; r++) mx[r] = fmaxf(mx[r], s[nt][r]);
  #pragma unroll
  for (int m = 1; m < 16; m <<= 1)
    #pragma unroll
    for (int r = 0; r < 4; r++) mx[r] = fmaxf(mx[r], __shfl_xor(mx[r], m, 64));
  float sum[4] = {0.f, 0.f, 0.f, 0.f};
  #pragma unroll
  for (int nt = 0; nt < 16; nt++)
    #pragma unroll
    for (int r = 0; r < 4; r++) {
      float e = __expf((s[nt][r] - mx[r]) * cs);
      s[nt][r] = e; sum[r] += e;
    }
  #pragma unroll
  for (int m = 1; m < 16; m <<= 1)
    #pragma unroll
    for (int r = 0; r < 4; r++) sum[r] += __shfl_xor(sum[r], m, 64);
  float inv[4];
  #pragma unroll
  for (int r = 0; r < 4; r++) inv[r] = 1.0f / sum[r];

  #pragma unroll
  for (int nt = 0; nt < 16; nt++)
    #pragma unroll
    for (int r = 0; r < 4; r++) {
      int row = kq * 4 + r;
      int col = nt * 16 + lr;
      Ps[w][row][col ^ ((row & 7) << 3)] = bf16bits(s[nt][r] * inv[r]);
    }
  __syncthreads();

  f32x4 o0 = {0.f, 0.f, 0.f, 0.f}, o1 = {0.f, 0.f, 0.f, 0.f};
  #pragma unroll
  for (int kc = 0; kc < 8; kc++) {
    short8 pf = *(const short8*)
        &Ps[w][lr][(kc ^ ((lr >> 2) & 1)) * 32 + (kq ^ (lr & 3)) * 8];
    int d0 = lr, d1 = 16 + lr;
    short8 vf0 = *(const short8*)&Vs[d0][(kc * 32 + kq * 8 + 8 * d0) & 255];
    short8 vf1 = *(const short8*)&Vs[d1][(kc * 32 + kq * 8 + 8 * d1) & 255];
    o0 = __builtin_amdgcn_mfma_f32_16x16x32_bf16(pf, vf0, o0, 0, 0, 0);
    o1 = __builtin_amdgcn_mfma_f32_16x16x32_bf16(pf, vf1, o1, 0, 0, 0);
  }

  #pragma unroll
  for (int r = 0; r < 4; r++) {
    int q = base + w * 16 + kq * 4 + r;
    ctx[(size_t)q * 256 + h * 32 + lr]      = __float2bfloat16(o0[r]);
    ctx[(size_t)q * 256 + h * 32 + 16 + lr] = __float2bfloat16(o1[r]);
  }
}

// ---------------- launch ----------------
extern "C" void kernel_launch(void* const* d_in, const int* in_sizes, int n_in,
                              void* d_out, int out_size, void* d_ws, size_t ws_size,
                              hipStream_t stream) {
  const void* x_in = d_in[0];
  const void* Wqkv = d_in[3];
  const void* bqkv = d_in[4];
  const void* Wo   = d_in[5];
  const void* bo   = d_in[6];
  const void* W1   = d_in[9];
  const void* b1   = d_in[10];
  const void* W2   = d_in[11];
  const void* b2   = d_in[12];
  const void* scale = d_in[13];

  // misc: flags(256B) + qkr(1MB) + sreg(512KB) + idx(8KB) + bits(1MB) + gsum/gsq(2KB)
  //       + bf16-transposed weights (1.5MB) ~= 4.21 MB
  const size_t MISC = 256 + 1048576 + 524288 + 8192 + 1048576 + 2048
                    + 393216 + 131072 + 524288 + 524288;
  int bcq, TC;
  if      (MISC + 16777216 <= ws_size) { bcq = 8; TC = 8192; }  // ~20.2 MB
  else if (MISC +  8388608 <= ws_size) { bcq = 4; TC = 4096; }  // ~12.2 MB (known fits)
  else                                 { bcq = 1; TC = 1024; }
  size_t r0 = (size_t)bcq * 2097152;   // qkvb (bcq*1.5MB) + ctxb (bcq*0.5MB)
  { size_t hb = (size_t)TC * 2048; if (hb > r0) r0 = hb; }

  char* ws = (char*)d_ws;
  int*  flags = (int*)ws;      // [0..13] per-input dtype; [14]=0 (bf16); [15]=1 (fp32)
  char* p = ws + 256;
  bf16* qkvb = (bf16*)p;
  bf16* ctxb = (bf16*)(p + (size_t)bcq * 1572864);
  bf16* hbuf = (bf16*)p;               // aliases qkvb/ctxb (disjoint phases)
  p += r0;
  float* qkr  = (float*)p;  p += 1048576;   // [512][512] (q||k routing projections)
  float* sreg = (float*)p;  p += 524288;    // [512][256] region means
  int*   idxb = (int*)p;    p += 8192;
  u64*   bits = (u64*)p;    p += 1048576;   // s1 bits, later s2 bits
  float* gsum = (float*)p;  p += 2048;
  float* gsq  = gsum + 256;
  bf16* wqkvt = (bf16*)p;   p += 393216;    // [768][256]
  bf16* wot   = (bf16*)p;   p += 131072;    // [256][256]
  bf16* w1t   = (bf16*)p;   p += 524288;    // [1024][256]
  bf16* w2t   = (bf16*)p;   p += 524288;    // [256][1024]
  float* out  = (float*)d_out;         // FP32 output: x_mid, then final (in place)
  const int* F14 = flags + 14;         // const bf16 flag (0)
  const int* F15 = flags + 15;         // const fp32 flag (1)

  // ---- dtype probes (one launch) ----
  hipMemsetAsync(flags, 0, 256, stream);
  PtrPack pk;
  for (int i = 0; i < 14; i++) { pk.p[i] = d_in[i]; pk.n[i] = in_sizes[i]; }
  probe_all_k<<<14, 64, 0, stream>>>(pk, flags);

  // ---- one-time weight transpose to bf16 [N][K] (one launch) ----
  wconv_all_k<<<3072, 256, 0, stream>>>(Wqkv, Wo, W1, W2, flags,
                                        wqkvt, wot, w1t, w2t);

  // ---- block 1: BN1 + LIF -> s1 bits ----
  hipMemsetAsync(gsum, 0, 512 * sizeof(float), stream);
  bnstats_k<<<256, 256, 0, stream>>>(x_in, flags + 0, gsum, gsq);
  lif_k<<<MT / 256, 256, 0, stream>>>(x_in, flags + 0, gsum, gsq,
                                      d_in[1], flags + 1, d_in[2], flags + 2, bits);

  // ---- region routing (fp32: exact top-k indices) ----
  regmean_k<<<512, 256, 0, stream>>>(bits, sreg);
  pgemm_k<<<dim3(8, 8), 256, 0, stream>>>(sreg, Wqkv, flags + 3, bqkv, flags + 4, qkr);
  afftopk_k<<<512, 256, 0, stream>>>(qkr, idxb);

  // ---- attention chunks: s1 bits -> qkv -> attn -> x_mid = x + scale*(ctx@Wo+bo) ----
  for (int t = 0; t < LTT; t++) {
    for (int b0 = 0; b0 < 8; b0 += bcq) {
      size_t tok0 = ((size_t)t * 8 + b0) * 1024;
      dgemm_k<3, 1><<<dim3(6, bcq * 8), 256, 0, stream>>>(
          (const void*)((const u32*)bits + tok0 * 8), wqkvt,
          bqkv, flags + 4, qkvb, nullptr, F14, nullptr, F14, 768, 256, 0);
      attn_k<<<bcq * 128, 256, 0, stream>>>(qkvb, idxb + (t * 8 + b0) * 64, ctxb);
      dgemm_k<4, 0><<<dim3(2, bcq * 8), 256, 0, stream>>>(
          ctxb, wot, bo, flags + 6, out, x_in, flags + 0,
          scale, flags + 13, 256, 256, tok0 * 256);
    }
  }

  // ---- block 2: BN2 + LIF on x_mid (fp32, in d_out) -> s2 bits ----
  hipMemsetAsync(gsum, 0, 512 * sizeof(float), stream);
  bnstats_k<<<256, 256, 0, stream>>>(out, F15, gsum, gsq);
  lif_k<<<MT / 256, 256, 0, stream>>>(out, F15, gsum, gsq,
                                      d_in[7], flags + 7, d_in[8], flags + 8, bits);

  // ---- FFN chunks: s2 bits -> gelu hidden -> out = x_mid + scale*(h@W2+b2) in place ----
  for (int c = 0; c * TC < NTOK; c++) {
    size_t tok0 = (size_t)c * TC;
    dgemm_k<2, 1><<<dim3(8, TC / 128), 256, 0, stream>>>(
        (const void*)((const u32*)bits + tok0 * 8), w1t,
        b1, flags + 10, hbuf, nullptr, F14, nullptr, F14, 1024, 256, 0);
    dgemm_k<4, 0><<<dim3(2, TC / 128), 256, 0, stream>>>(
        hbuf, w2t, b2, flags + 12, out, out, F15,
        scale, flags + 13, 256, 1024, tok0 * 256);
  }
}

// Round 4
// 487.029 us; speedup vs baseline: 6.5805x; 1.4734x over previous
//
#include <hip/hip_runtime.h>
#include <hip/hip_bf16.h>
#include <math.h>

typedef __hip_bfloat16 bf16;
typedef unsigned long long u64;
typedef unsigned int u32;

#define LTT 4
#define DIM 256
#define NTOK 32768      // total tokens (4*8*1024)
#define MT 2097152      // elements per time step (8192 tokens * 256)
#define NTOT 8388608

typedef __attribute__((ext_vector_type(8))) short short8;   // 8 bf16 (4 VGPRs)
typedef __attribute__((ext_vector_type(4))) float f32x4;
typedef __attribute__((ext_vector_type(4))) u32 u32x4;

// dual-dtype load with finite clamp: f=1 -> fp32, f=0 -> bf16
__device__ __forceinline__ float ldin(const void* p, size_t i, int f) {
  float v = f ? ((const float*)p)[i] : __bfloat162float(((const bf16*)p)[i]);
  return isfinite(v) ? v : 0.0f;
}

__device__ __forceinline__ short bf16bits(float x) {
  union { bf16 b; short s; } u; u.b = __float2bfloat16(x); return u.s;
}

// ---------------- per-input dtype probes, all inputs in one launch ----------------
struct PtrPack { const void* p[14]; int n[14]; };

__global__ void probe_all_k(PtrPack pk, int* flags) {
  int b = blockIdx.x;            // 14 blocks, one per input
  int tid = threadIdx.x;         // 64
  const unsigned short* u = (const unsigned short*)pk.p[b];
  int nelem = pk.n[b];
  int n = nelem < 1024 ? nelem : 1024;
  bool big = false, nz = false;
  for (int i = tid; i < n; i += 64) {
    unsigned short h = u[i];
    if (((h >> 7) & 0xFF) >= 0xC0) big = true;
    if (h != 0) nz = true;
  }
  u64 bm = __ballot(big);
  u64 zm = __ballot(nz);
  if (tid == 0) {
    unsigned short h0 = u[0];
    int f = 0;
    if (bm != 0ull) f = 1;
    else if (h0 == 0 && (zm != 0ull || n == 1)) f = 1;
    flags[b] = f;
    if (b == 0) flags[15] = 1;   // const fp32 flag
  }
}

// ---------------- batchnorm stats: per-channel sums over 32768 tokens ----------------
__global__ void bnstats_k(const void* __restrict__ x, const int* __restrict__ fxp,
                          float* __restrict__ gsum, float* __restrict__ gsq) {
  int fx = *fxp;
  int c = threadIdx.x;            // 256 channels
  int tok0 = blockIdx.x * 128;    // 256 blocks * 128 tokens
  float s = 0.f, q = 0.f;
  for (int t = 0; t < 128; t++) {
    float v = ldin(x, (size_t)(tok0 + t) * DIM + c, fx);
    s += v; q += v * v;
  }
  atomicAdd(&gsum[c], s);
  atomicAdd(&gsq[c], q);
}

// ---------------- fused BN-apply + LIF scan over t; spikes bit-packed ----------------
__global__ void lif_k(const void* __restrict__ x, const int* __restrict__ fxp,
                      const float* __restrict__ gsum, const float* __restrict__ gsq,
                      const void* __restrict__ gamma, const int* __restrict__ fgp,
                      const void* __restrict__ beta, const int* __restrict__ fbp,
                      u64* __restrict__ bits) {
  int fx = *fxp, fg = *fgp, fb = *fbp;
  int m = blockIdx.x * 256 + threadIdx.x;   // [0, MT)
  int c = m & (DIM - 1);
  int lane = threadIdx.x & 63;
  float mean = gsum[c] * (1.0f / 32768.0f);
  float var  = gsq[c] * (1.0f / 32768.0f) - mean * mean;
  float inv  = rsqrtf(var + 1e-5f);
  float g = ldin(gamma, c, fg), be = ldin(beta, c, fb);
  float v = 0.f;
  #pragma unroll
  for (int t = 0; t < LTT; t++) {
    size_t e = (size_t)t * MT + m;
    float xn = (ldin(x, e, fx) - mean) * inv * g + be;
    v = v + (xn - v) * 0.5f;                 // TAU = 2
    bool sp = (v - 1.0f >= 0.0f);            // VTH = 1
    u64 bl = __ballot(sp);
    if (lane == 0) bits[e >> 6] = bl;        // e>>6 is wave-uniform
    v = sp ? 0.0f : v;
  }
}

__device__ __forceinline__ float gelu_f(float x) {
  return 0.5f * x * (1.0f + erff(x * 0.70710678118654752440f));
}

// ---------------- one-time weight convert+transpose (all 4 weights, one launch) ----
// W[K][N] (flag dtype) -> Wt[N][K] bf16
__global__ void wconv_all_k(const void* __restrict__ Wqkv, const void* __restrict__ Wo,
                            const void* __restrict__ W1, const void* __restrict__ W2,
                            const int* __restrict__ flags,
                            bf16* __restrict__ wqkvt, bf16* __restrict__ wot,
                            bf16* __restrict__ w1t, bf16* __restrict__ w2t) {
  int b = blockIdx.x, t = threadIdx.x;
  const void* W; const int* f; bf16* o; int K, N, n, kblk = 0;
  if (b < 768)       { W = Wqkv; f = flags + 3;  o = wqkvt; K = 256;  N = 768;  n = b; }
  else if (b < 1024) { W = Wo;   f = flags + 5;  o = wot;   K = 256;  N = 256;  n = b - 768; }
  else if (b < 2048) { W = W1;   f = flags + 9;  o = w1t;   K = 256;  N = 1024; n = b - 1024; }
  else { W = W2; f = flags + 11; o = w2t; K = 1024; N = 256;
         int q = b - 2048; kblk = q >> 8; n = q & 255; }
  int k = kblk * 256 + t;
  o[(size_t)n * K + k] = __float2bfloat16(ldin(W, (size_t)k * N + n, *f));
}

// ---------------- LDS-free direct MFMA GEMM, 128x128 tile, 4 waves ----------------
// (used for qkv spike GEMM and the Wo projection; FFN is fused in ffn_k)
template <int MODE, int ABITS>
__global__ void __launch_bounds__(256)
dgemm_k(const void* __restrict__ Av, const bf16* __restrict__ Bt,
        const void* __restrict__ biasv, const int* __restrict__ fbp,
        void* O, const void* xinv, const int* __restrict__ fxp,
        const void* __restrict__ scalev, const int* __restrict__ fsp,
        int N, int K, size_t obase) {
  int tid = threadIdx.x;
  int lane = tid & 63, w = tid >> 6;
  int wr = w >> 1, wc = w & 1;          // wave -> 64x64 quadrant
  int kq = lane >> 4, lr = lane & 15;
  int bm = blockIdx.y * 128, bn = blockIdx.x * 128;
  f32x4 acc[4][4] = {};

  if constexpr (ABITS) {
    // K = 256 fixed for spike GEMMs.
    __shared__ __align__(16) short lut[256][8];
    {
      short8 e;
      #pragma unroll
      for (int j = 0; j < 8; j++) e[j] = ((tid >> j) & 1) ? (short)0x3F80 : (short)0;
      *(short8*)&lut[tid][0] = e;
    }
    const u32* Abits = (const u32*)Av;
    u32 ab[4][8];
    #pragma unroll
    for (int i = 0; i < 4; i++) {
      const u32* rp = &Abits[(size_t)(bm + wr * 64 + i * 16 + lr) * 8];
      *(u32x4*)&ab[i][0] = *(const u32x4*)&rp[0];
      *(u32x4*)&ab[i][4] = *(const u32x4*)&rp[4];
    }
    __syncthreads();
    #pragma unroll
    for (int s = 0; s < 8; s++) {        // k0 = s*32
      short8 af[4], bf[4];
      #pragma unroll
      for (int i = 0; i < 4; i++) {
        u32 byte = (ab[i][s] >> (kq * 8)) & 0xFFu;
        af[i] = *(const short8*)&lut[byte][0];
      }
      #pragma unroll
      for (int j = 0; j < 4; j++)
        bf[j] = *(const short8*)&Bt[(size_t)(bn + wc * 64 + j * 16 + lr) * 256 + s * 32 + kq * 8];
      #pragma unroll
      for (int i = 0; i < 4; i++)
        #pragma unroll
        for (int j = 0; j < 4; j++)
          acc[i][j] = __builtin_amdgcn_mfma_f32_16x16x32_bf16(af[i], bf[j], acc[i][j], 0, 0, 0);
    }
  } else {
    const bf16* Ab = (const bf16*)Av;
    for (int k0 = 0; k0 < K; k0 += 32) {
      short8 af[4], bf[4];
      #pragma unroll
      for (int i = 0; i < 4; i++)
        af[i] = *(const short8*)&Ab[(size_t)(bm + wr * 64 + i * 16 + lr) * K + k0 + kq * 8];
      #pragma unroll
      for (int j = 0; j < 4; j++)
        bf[j] = *(const short8*)&Bt[(size_t)(bn + wc * 64 + j * 16 + lr) * K + k0 + kq * 8];
      #pragma unroll
      for (int i = 0; i < 4; i++)
        #pragma unroll
        for (int j = 0; j < 4; j++)
          acc[i][j] = __builtin_amdgcn_mfma_f32_16x16x32_bf16(af[i], bf[j], acc[i][j], 0, 0, 0);
    }
  }

  // epilogue: D layout col=lane&15, row=(lane>>4)*4+r (verified mapping)
  float scl = 0.f;
  int fx = 0, fbias = *fbp;
  if (MODE == 4) { scl = ldin(scalev, 0, *fsp); fx = *fxp; }
  int row0 = bm + wr * 64 + kq * 4;
  int col0 = bn + wc * 64 + lr;
  #pragma unroll
  for (int j = 0; j < 4; j++) {
    int n = col0 + j * 16;
    float bb = ldin(biasv, n, fbias);
    #pragma unroll
    for (int i = 0; i < 4; i++) {
      #pragma unroll
      for (int r = 0; r < 4; r++) {
        int m = row0 + i * 16 + r;
        float v = acc[i][j][r] + bb;
        size_t o = obase + (size_t)m * N + n;
        if (MODE == 2) {
          ((bf16*)O)[o] = __float2bfloat16(gelu_f(v));
        } else if (MODE == 3) {
          ((bf16*)O)[o] = __float2bfloat16(v);
        } else {
          float base = ldin(xinv, o, fx);
          ((float*)O)[o] = base + scl * v;
        }
      }
    }
  }
}

// ---------------- fused FFN: out += scl*(gelu(spikes@W1+b1)@W2+b2), no hidden buffer ----
// 512 blocks x 64 tokens. Per 128-hidden chunk: phase A (spike MFMA -> gelu -> LDS
// [kb][row][8] bf16), barrier, phase B (MFMA into persistent 64x256 accumulator).
__global__ void __launch_bounds__(256)
ffn_k(const u64* __restrict__ bits_, const bf16* __restrict__ w1t,
      const void* __restrict__ b1v, const int* __restrict__ f1p,
      const bf16* __restrict__ w2t,
      const void* __restrict__ b2v, const int* __restrict__ f2p,
      float* out, const void* __restrict__ scalev, const int* __restrict__ fsp) {
  __shared__ __align__(16) short lut[256][8];     // 4 KB byte->8xbf16
  __shared__ __align__(16) short hlds[16][64][8]; // 16 KB h chunk [64][128]
  int tid = threadIdx.x;
  int lane = tid & 63, w = tid >> 6;
  int kq = lane >> 4, lr = lane & 15;
  int m0 = blockIdx.x * 64;
  {
    short8 e;
    #pragma unroll
    for (int j = 0; j < 8; j++) e[j] = ((tid >> j) & 1) ? (short)0x3F80 : (short)0;
    *(short8*)&lut[tid][0] = e;
  }
  const u32* Abits = (const u32*)bits_;
  u32 ab[4][8];
  #pragma unroll
  for (int i = 0; i < 4; i++) {
    const u32* rp = &Abits[(size_t)(m0 + i * 16 + lr) * 8];
    *(u32x4*)&ab[i][0] = *(const u32x4*)&rp[0];
    *(u32x4*)&ab[i][4] = *(const u32x4*)&rp[4];
  }
  int f1 = *f1p;
  f32x4 acc2[4][4] = {};
  __syncthreads();

  for (int c = 0; c < 8; c++) {
    // ---- phase A: h[64][128] for hidden cols c*128..; wave w -> cols w*32..+32
    f32x4 accA[4][2] = {};
    #pragma unroll
    for (int s = 0; s < 8; s++) {
      short8 af[4], bf2[2];
      #pragma unroll
      for (int i = 0; i < 4; i++) {
        u32 byte = (ab[i][s] >> (kq * 8)) & 0xFFu;
        af[i] = *(const short8*)&lut[byte][0];
      }
      #pragma unroll
      for (int j = 0; j < 2; j++)
        bf2[j] = *(const short8*)&w1t[(size_t)(c * 128 + w * 32 + j * 16 + lr) * 256 + s * 32 + kq * 8];
      #pragma unroll
      for (int i = 0; i < 4; i++)
        #pragma unroll
        for (int j = 0; j < 2; j++)
          accA[i][j] = __builtin_amdgcn_mfma_f32_16x16x32_bf16(af[i], bf2[j], accA[i][j], 0, 0, 0);
    }
    // gelu + bf16 -> hlds[cl>>3][row][cl&7]
    #pragma unroll
    for (int j = 0; j < 2; j++) {
      int cl = w * 32 + j * 16 + lr;          // col within 128-chunk
      float bb = ldin(b1v, c * 128 + cl, f1);
      #pragma unroll
      for (int i = 0; i < 4; i++)
        #pragma unroll
        for (int r = 0; r < 4; r++) {
          int row = i * 16 + kq * 4 + r;
          hlds[cl >> 3][row][cl & 7] = bf16bits(gelu_f(accA[i][j][r] + bb));
        }
    }
    __syncthreads();
    // ---- phase B: acc2 += h_chunk @ W2[c*128.., :]; wave w -> out cols w*64..+64
    #pragma unroll
    for (int ks = 0; ks < 4; ks++) {
      short8 af[4], bf4[4];
      #pragma unroll
      for (int i = 0; i < 4; i++)
        af[i] = *(const short8*)&hlds[ks * 4 + kq][i * 16 + lr][0];
      #pragma unroll
      for (int j = 0; j < 4; j++)
        bf4[j] = *(const short8*)&w2t[(size_t)(w * 64 + j * 16 + lr) * 1024 + c * 128 + ks * 32 + kq * 8];
      #pragma unroll
      for (int i = 0; i < 4; i++)
        #pragma unroll
        for (int j = 0; j < 4; j++)
          acc2[i][j] = __builtin_amdgcn_mfma_f32_16x16x32_bf16(af[i], bf4[j], acc2[i][j], 0, 0, 0);
    }
    __syncthreads();
  }

  float scl = ldin(scalev, 0, *fsp);
  int f2 = *f2p;
  #pragma unroll
  for (int j = 0; j < 4; j++) {
    int n = w * 64 + j * 16 + lr;
    float bb = ldin(b2v, n, f2);
    #pragma unroll
    for (int i = 0; i < 4; i++)
      #pragma unroll
      for (int r = 0; r < 4; r++) {
        int row = m0 + i * 16 + kq * 4 + r;
        size_t o = (size_t)row * 256 + n;
        out[o] = out[o] + scl * (acc2[i][j][r] + bb);  // same-thread read-then-write
      }
  }
}

// ---------------- region-mean of spike bits: sreg[512][256] fp32 ----------------
__global__ void regmean_k(const u64* __restrict__ bits, float* __restrict__ sreg) {
  int blk = blockIdx.x;   // 512 regions
  int c = threadIdx.x;    // 256
  float s = 0.f;
  for (int i = 0; i < 64; i++) {
    u64 w = bits[(size_t)(blk * 64 + i) * 4 + (c >> 6)];
    s += (float)((w >> (c & 63)) & 1ull);
  }
  sreg[(size_t)blk * 256 + c] = s * (1.0f / 64.0f);
}

// ---------------- routing projection: qkr[512][512] = sreg @ Wqkv[:, :512] + bqkv ----
__global__ void __launch_bounds__(256)
pgemm_k(const float* __restrict__ A,          // sreg [512][256]
        const void* __restrict__ Bv, const int* __restrict__ fBp,   // Wqkv, row stride 768
        const void* __restrict__ biasv, const int* __restrict__ fbp,
        float* __restrict__ Oq) {             // qkr [512][512]
  int fB = *fBp, fb = *fbp;
  __shared__ float Ast[16][68];
  __shared__ float Bs[16][68];
  int tid = threadIdx.x;
  int bm = blockIdx.y * 64, bn = blockIdx.x * 64;
  int tr = tid >> 4, tc = tid & 15;
  float acc[4][4] = {};
  for (int k0 = 0; k0 < 256; k0 += 16) {
    for (int t = tid; t < 1024; t += 256) {
      int m = t >> 4, k = t & 15;
      Ast[k][m] = A[(size_t)(bm + m) * 256 + k0 + k];
    }
    for (int t = tid; t < 1024; t += 256) {
      int k = t >> 6, n = t & 63;
      Bs[k][n] = ldin(Bv, (size_t)(k0 + k) * 768 + bn + n, fB);
    }
    __syncthreads();
    #pragma unroll
    for (int kk = 0; kk < 16; kk++) {
      float4 a4 = *(const float4*)&Ast[kk][tr * 4];
      float4 b4 = *(const float4*)&Bs[kk][tc * 4];
      float a[4] = {a4.x, a4.y, a4.z, a4.w};
      float b[4] = {b4.x, b4.y, b4.z, b4.w};
      #pragma unroll
      for (int i = 0; i < 4; i++)
        #pragma unroll
        for (int jj = 0; jj < 4; jj++)
          acc[i][jj] += a[i] * b[jj];
    }
    __syncthreads();
  }
  #pragma unroll
  for (int i = 0; i < 4; i++)
    #pragma unroll
    for (int jj = 0; jj < 4; jj++) {
      int n = bn + tc * 4 + jj;
      Oq[(size_t)(bm + tr * 4 + i) * 512 + n] = acc[i][jj] + ldin(biasv, n, fb);
    }
}

// ---------------- affinity + top-4 (ties -> lowest index, matches lax.top_k) ----------------
__global__ void afftopk_k(const float* __restrict__ qkr, int* __restrict__ idx) {
  int blk = blockIdx.x;       // (t*8+b)*16 + r
  int tb = blk >> 4;
  int tid = threadIdx.x;      // 256
  int s_ = tid >> 4, p = tid & 15;
  __shared__ float part[256];
  __shared__ float aff[16];
  const float* qrow = qkr + (size_t)blk * 512;                 // q half
  const float* krow = qkr + (size_t)(tb * 16 + s_) * 512 + 256; // k half
  float acc = 0.f;
  for (int c = p * 16; c < p * 16 + 16; c++) acc += qrow[c] * krow[c];
  part[tid] = acc;
  __syncthreads();
  if (tid < 16) {
    float a = 0.f;
    for (int pp = 0; pp < 16; pp++) a += part[tid * 16 + pp];
    aff[tid] = a;
  }
  __syncthreads();
  if (tid == 0) {
    bool taken[16] = {};
    for (int kk = 0; kk < 4; kk++) {
      float best = -INFINITY; int bi = 0;
      for (int i = 0; i < 16; i++)
        if (!taken[i] && aff[i] > best) { best = aff[i]; bi = i; }
      taken[bi] = true;
      idx[blk * 4 + kk] = bi;
    }
  }
}

// ---------------- MFMA gathered attention per (b_local, r, h) ----------------
__global__ void __launch_bounds__(256)
attn_k(const bf16* __restrict__ qkv, const int* __restrict__ idx,
       bf16* __restrict__ ctx) {
  __shared__ __align__(16) short Ks[256][32];     // 16 KB
  __shared__ __align__(16) short Vs[32][256];     // 16 KB (rotated V^T)
  __shared__ __align__(16) short Ps[4][16][256];  // 32 KB (per-wave P, swizzled)
  int blk = blockIdx.x;             // (b_local*16+r)*8 + h
  int h = blk & 7, br = blk >> 3;
  int b = br >> 4;                  // chunk-local batch
  int tid = threadIdx.x;
  int base = br * 64;               // chunk-local token base
  int r0 = idx[br * 4 + 0], r1 = idx[br * 4 + 1];
  int r2 = idx[br * 4 + 2], r3 = idx[br * 4 + 3];

  #pragma unroll
  for (int c = 0; c < 4; c++) {
    int g = c * 256 + tid;
    int tk = g >> 2, ch = g & 3;
    int rs = tk >> 6;
    int rid = (rs & 2) ? ((rs & 1) ? r3 : r2) : ((rs & 1) ? r1 : r0);
    int gt = b * 1024 + rid * 64 + (tk & 63);
    short8 v = *(const short8*)&qkv[(size_t)gt * 768 + 256 + h * 32 + ch * 8];
    *(short8*)&Ks[tk][ch * 8] = v;
  }
  {
    int tk = tid;
    int rs = tk >> 6;
    int rid = (rs & 2) ? ((rs & 1) ? r3 : r2) : ((rs & 1) ? r1 : r0);
    int gt = b * 1024 + rid * 64 + (tk & 63);
    const bf16* vp = &qkv[(size_t)gt * 768 + 512 + h * 32];
    short vv[32];
    *(short8*)&vv[0]  = *(const short8*)&vp[0];
    *(short8*)&vv[8]  = *(const short8*)&vp[8];
    *(short8*)&vv[16] = *(const short8*)&vp[16];
    *(short8*)&vv[24] = *(const short8*)&vp[24];
    #pragma unroll
    for (int d = 0; d < 32; d++)
      Vs[d][(tk + 8 * d) & 255] = vv[d];
  }
  __syncthreads();

  int w = tid >> 6, lane = tid & 63, kq = lane >> 4, lr = lane & 15;

  short8 qf = *(const short8*)&qkv[(size_t)(base + w * 16 + lr) * 768 + h * 32 + kq * 8];

  f32x4 s[16];
  #pragma unroll
  for (int nt = 0; nt < 16; nt++) {
    short8 kf = *(const short8*)&Ks[nt * 16 + lr][kq * 8];
    f32x4 z = {0.f, 0.f, 0.f, 0.f};
    s[nt] = __builtin_amdgcn_mfma_f32_16x16x32_bf16(qf, kf, z, 0, 0, 0);
  }

  const float cs = 0.17677669529663687f;   // 1/sqrt(32)
  float mx[4] = {-INFINITY, -INFINITY, -INFINITY, -INFINITY};
  #pragma unroll
  for (int nt = 0; nt < 16; nt++)
    #pragma unroll
    for (int r = 0; r < 4; r++) mx[r] = fmaxf(mx[r], s[nt][r]);
  #pragma unroll
  for (int m = 1; m < 16; m <<= 1)
    #pragma unroll
    for (int r = 0; r < 4; r++) mx[r] = fmaxf(mx[r], __shfl_xor(mx[r], m, 64));
  float sum[4] = {0.f, 0.f, 0.f, 0.f};
  #pragma unroll
  for (int nt = 0; nt < 16; nt++)
    #pragma unroll
    for (int r = 0; r < 4; r++) {
      float e = __expf((s[nt][r] - mx[r]) * cs);
      s[nt][r] = e; sum[r] += e;
    }
  #pragma unroll
  for (int m = 1; m < 16; m <<= 1)
    #pragma unroll
    for (int r = 0; r < 4; r++) sum[r] += __shfl_xor(sum[r], m, 64);
  float inv[4];
  #pragma unroll
  for (int r = 0; r < 4; r++) inv[r] = 1.0f / sum[r];

  #pragma unroll
  for (int nt = 0; nt < 16; nt++)
    #pragma unroll
    for (int r = 0; r < 4; r++) {
      int row = kq * 4 + r;
      int col = nt * 16 + lr;
      Ps[w][row][col ^ ((row & 7) << 3)] = bf16bits(s[nt][r] * inv[r]);
    }
  __syncthreads();

  f32x4 o0 = {0.f, 0.f, 0.f, 0.f}, o1 = {0.f, 0.f, 0.f, 0.f};
  #pragma unroll
  for (int kc = 0; kc < 8; kc++) {
    short8 pf = *(const short8*)
        &Ps[w][lr][(kc ^ ((lr >> 2) & 1)) * 32 + (kq ^ (lr & 3)) * 8];
    int d0 = lr, d1 = 16 + lr;
    short8 vf0 = *(const short8*)&Vs[d0][(kc * 32 + kq * 8 + 8 * d0) & 255];
    short8 vf1 = *(const short8*)&Vs[d1][(kc * 32 + kq * 8 + 8 * d1) & 255];
    o0 = __builtin_amdgcn_mfma_f32_16x16x32_bf16(pf, vf0, o0, 0, 0, 0);
    o1 = __builtin_amdgcn_mfma_f32_16x16x32_bf16(pf, vf1, o1, 0, 0, 0);
  }

  #pragma unroll
  for (int r = 0; r < 4; r++) {
    int q = base + w * 16 + kq * 4 + r;
    ctx[(size_t)q * 256 + h * 32 + lr]      = __float2bfloat16(o0[r]);
    ctx[(size_t)q * 256 + h * 32 + 16 + lr] = __float2bfloat16(o1[r]);
  }
}

// ---------------- launch ----------------
extern "C" void kernel_launch(void* const* d_in, const int* in_sizes, int n_in,
                              void* d_out, int out_size, void* d_ws, size_t ws_size,
                              hipStream_t stream) {
  const void* x_in = d_in[0];
  const void* Wqkv = d_in[3];
  const void* bqkv = d_in[4];
  const void* Wo   = d_in[5];
  const void* bo   = d_in[6];
  const void* W1   = d_in[9];
  const void* b1   = d_in[10];
  const void* W2   = d_in[11];
  const void* b2   = d_in[12];
  const void* scale = d_in[13];

  // misc: flags(256B) + qkr(1MB) + sreg(512KB) + idx(8KB) + bits(1MB) + gsum/gsq(2KB)
  //       + bf16-transposed weights (1.5MB) ~= 4.1 MB. No hidden buffer (FFN fused).
  const size_t MISC = 256 + 1048576 + 524288 + 8192 + 1048576 + 2048
                    + 393216 + 131072 + 524288 + 524288;
  int C;  // batches (of 1024 tokens) per attention chunk; 32 = whole tensor
  if      (MISC + (size_t)32 * 2097152 <= ws_size) C = 32;   // ~68.2 MB
  else if (MISC + (size_t)8  * 2097152 <= ws_size) C = 8;    // ~20.9 MB
  else if (MISC + (size_t)4  * 2097152 <= ws_size) C = 4;    // ~12.5 MB
  else                                             C = 1;
  size_t r0 = (size_t)C * 2097152;   // qkvb (C*1.5MB) + ctxb (C*0.5MB)

  char* ws = (char*)d_ws;
  int*  flags = (int*)ws;      // [0..13] per-input dtype; [14]=0 (bf16); [15]=1 (fp32)
  char* p = ws + 256;
  bf16* qkvb = (bf16*)p;
  bf16* ctxb = (bf16*)(p + (size_t)C * 1572864);
  p += r0;
  float* qkr  = (float*)p;  p += 1048576;   // [512][512] (q||k routing projections)
  float* sreg = (float*)p;  p += 524288;    // [512][256] region means
  int*   idxb = (int*)p;    p += 8192;
  u64*   bits = (u64*)p;    p += 1048576;   // s1 bits, later s2 bits
  float* gsum = (float*)p;  p += 2048;
  float* gsq  = gsum + 256;
  bf16* wqkvt = (bf16*)p;   p += 393216;    // [768][256]
  bf16* wot   = (bf16*)p;   p += 131072;    // [256][256]
  bf16* w1t   = (bf16*)p;   p += 524288;    // [1024][256]
  bf16* w2t   = (bf16*)p;   p += 524288;    // [256][1024]
  float* out  = (float*)d_out;         // FP32 output: x_mid, then final (in place)
  const int* F14 = flags + 14;         // const bf16 flag (0)

  // ---- dtype probes (one launch) ----
  hipMemsetAsync(flags, 0, 256, stream);
  PtrPack pk;
  for (int i = 0; i < 14; i++) { pk.p[i] = d_in[i]; pk.n[i] = in_sizes[i]; }
  probe_all_k<<<14, 64, 0, stream>>>(pk, flags);

  // ---- one-time weight transpose to bf16 [N][K] (one launch) ----
  wconv_all_k<<<3072, 256, 0, stream>>>(Wqkv, Wo, W1, W2, flags,
                                        wqkvt, wot, w1t, w2t);

  // ---- block 1: BN1 + LIF -> s1 bits ----
  hipMemsetAsync(gsum, 0, 512 * sizeof(float), stream);
  bnstats_k<<<256, 256, 0, stream>>>(x_in, flags + 0, gsum, gsq);
  lif_k<<<MT / 256, 256, 0, stream>>>(x_in, flags + 0, gsum, gsq,
                                      d_in[1], flags + 1, d_in[2], flags + 2, bits);

  // ---- region routing (fp32: exact top-k indices) ----
  regmean_k<<<512, 256, 0, stream>>>(bits, sreg);
  pgemm_k<<<dim3(8, 8), 256, 0, stream>>>(sreg, Wqkv, flags + 3, bqkv, flags + 4, qkr);
  afftopk_k<<<512, 256, 0, stream>>>(qkr, idxb);

  // ---- attention chunks over (t,b) batches: qkv -> attn -> x_mid = x + scl*(ctx@Wo+bo) ----
  for (int gb = 0; gb < 32; gb += C) {
    size_t tok0 = (size_t)gb * 1024;
    dgemm_k<3, 1><<<dim3(6, C * 8), 256, 0, stream>>>(
        (const void*)((const u32*)bits + tok0 * 8), wqkvt,
        bqkv, flags + 4, qkvb, nullptr, F14, nullptr, F14, 768, 256, 0);
    attn_k<<<C * 128, 256, 0, stream>>>(qkvb, idxb + gb * 64, ctxb);
    dgemm_k<4, 0><<<dim3(2, C * 8), 256, 0, stream>>>(
        ctxb, wot, bo, flags + 6, out, x_in, flags + 0,
        scale, flags + 13, 256, 256, tok0 * 256);
  }

  // ---- block 2: BN2 + LIF on x_mid (fp32, in d_out) -> s2 bits ----
  hipMemsetAsync(gsum, 0, 512 * sizeof(float), stream);
  bnstats_k<<<256, 256, 0, stream>>>(out, flags + 15, gsum, gsq);
  lif_k<<<MT / 256, 256, 0, stream>>>(out, flags + 15, gsum, gsq,
                                      d_in[7], flags + 7, d_in[8], flags + 8, bits);

  // ---- fused FFN: one launch over all 32768 tokens ----
  ffn_k<<<NTOK / 64, 256, 0, stream>>>(bits, w1t, b1, flags + 10,
                                       w2t, b2, flags + 12,
                                       out, scale, flags + 13);
}

// Round 5
// 440.433 us; speedup vs baseline: 7.2767x; 1.1058x over previous
//
#include <hip/hip_runtime.h>
#include <hip/hip_bf16.h>
#include <math.h>

typedef __hip_bfloat16 bf16;
typedef unsigned long long u64;
typedef unsigned int u32;

#define LTT 4
#define DIM 256
#define NTOK 32768      // total tokens (4*8*1024)
#define MT 2097152      // elements per time step (8192 tokens * 256)
#define NTOT 8388608

typedef __attribute__((ext_vector_type(8))) short short8;   // 8 bf16 (4 VGPRs)
typedef __attribute__((ext_vector_type(4))) float f32x4;
typedef __attribute__((ext_vector_type(4))) u32 u32x4;

// dual-dtype load with finite clamp: f=1 -> fp32, f=0 -> bf16
__device__ __forceinline__ float ldin(const void* p, size_t i, int f) {
  float v = f ? ((const float*)p)[i] : __bfloat162float(((const bf16*)p)[i]);
  return isfinite(v) ? v : 0.0f;
}

__device__ __forceinline__ short bf16bits(float x) {
  union { bf16 b; short s; } u; u.b = __float2bfloat16(x); return u.s;
}

// ---------------- per-input dtype probes, all inputs in one launch ----------------
struct PtrPack { const void* p[14]; int n[14]; };

__global__ void probe_all_k(PtrPack pk, int* flags) {
  int b = blockIdx.x;            // 14 blocks, one per input
  int tid = threadIdx.x;         // 64
  const unsigned short* u = (const unsigned short*)pk.p[b];
  int nelem = pk.n[b];
  int n = nelem < 1024 ? nelem : 1024;
  bool big = false, nz = false;
  for (int i = tid; i < n; i += 64) {
    unsigned short h = u[i];
    if (((h >> 7) & 0xFF) >= 0xC0) big = true;
    if (h != 0) nz = true;
  }
  u64 bm = __ballot(big);
  u64 zm = __ballot(nz);
  if (tid == 0) {
    unsigned short h0 = u[0];
    int f = 0;
    if (bm != 0ull) f = 1;
    else if (h0 == 0 && (zm != 0ull || n == 1)) f = 1;
    flags[b] = f;
    if (b == 0) flags[15] = 1;   // const fp32 flag
  }
}

// ---------------- batchnorm stats: per-channel sums over 32768 tokens ----------------
__global__ void bnstats_k(const void* __restrict__ x, const int* __restrict__ fxp,
                          float* __restrict__ gsum, float* __restrict__ gsq) {
  int fx = *fxp;
  int c = threadIdx.x;            // 256 channels
  int tok0 = blockIdx.x * 128;    // 256 blocks * 128 tokens
  float s = 0.f, q = 0.f;
  for (int t = 0; t < 128; t++) {
    float v = ldin(x, (size_t)(tok0 + t) * DIM + c, fx);
    s += v; q += v * v;
  }
  atomicAdd(&gsum[c], s);
  atomicAdd(&gsq[c], q);
}

// ---------------- fused BN-apply + LIF scan over t; spikes bit-packed ----------------
__global__ void lif_k(const void* __restrict__ x, const int* __restrict__ fxp,
                      const float* __restrict__ gsum, const float* __restrict__ gsq,
                      const void* __restrict__ gamma, const int* __restrict__ fgp,
                      const void* __restrict__ beta, const int* __restrict__ fbp,
                      u64* __restrict__ bits) {
  int fx = *fxp, fg = *fgp, fb = *fbp;
  int m = blockIdx.x * 256 + threadIdx.x;   // [0, MT)
  int c = m & (DIM - 1);
  int lane = threadIdx.x & 63;
  float mean = gsum[c] * (1.0f / 32768.0f);
  float var  = gsq[c] * (1.0f / 32768.0f) - mean * mean;
  float inv  = rsqrtf(var + 1e-5f);
  float g = ldin(gamma, c, fg), be = ldin(beta, c, fb);
  float v = 0.f;
  #pragma unroll
  for (int t = 0; t < LTT; t++) {
    size_t e = (size_t)t * MT + m;
    float xn = (ldin(x, e, fx) - mean) * inv * g + be;
    v = v + (xn - v) * 0.5f;                 // TAU = 2
    bool sp = (v - 1.0f >= 0.0f);            // VTH = 1
    u64 bl = __ballot(sp);
    if (lane == 0) bits[e >> 6] = bl;        // e>>6 is wave-uniform
    v = sp ? 0.0f : v;
  }
}

__device__ __forceinline__ float gelu_f(float x) {
  return 0.5f * x * (1.0f + erff(x * 0.70710678118654752440f));
}

// ---------------- one-time weight convert+transpose (all 4 weights, one launch) ----
// W[K][N] (flag dtype) -> Wt[N][K] bf16
__global__ void wconv_all_k(const void* __restrict__ Wqkv, const void* __restrict__ Wo,
                            const void* __restrict__ W1, const void* __restrict__ W2,
                            const int* __restrict__ flags,
                            bf16* __restrict__ wqkvt, bf16* __restrict__ wot,
                            bf16* __restrict__ w1t, bf16* __restrict__ w2t) {
  int b = blockIdx.x, t = threadIdx.x;
  const void* W; const int* f; bf16* o; int K, N, n, kblk = 0;
  if (b < 768)       { W = Wqkv; f = flags + 3;  o = wqkvt; K = 256;  N = 768;  n = b; }
  else if (b < 1024) { W = Wo;   f = flags + 5;  o = wot;   K = 256;  N = 256;  n = b - 768; }
  else if (b < 2048) { W = W1;   f = flags + 9;  o = w1t;   K = 256;  N = 1024; n = b - 1024; }
  else { W = W2; f = flags + 11; o = w2t; K = 1024; N = 256;
         int q = b - 2048; kblk = q >> 8; n = q & 255; }
  int k = kblk * 256 + t;
  o[(size_t)n * K + k] = __float2bfloat16(ldin(W, (size_t)k * N + n, *f));
}

// ---------------- LDS-free direct MFMA GEMM, 128x128 tile, 4 waves ----------------
// (used for qkv spike GEMM and the Wo projection; FFN is fused in ffn_k)
template <int MODE, int ABITS>
__global__ void __launch_bounds__(256)
dgemm_k(const void* __restrict__ Av, const bf16* __restrict__ Bt,
        const void* __restrict__ biasv, const int* __restrict__ fbp,
        void* O, const void* xinv, const int* __restrict__ fxp,
        const void* __restrict__ scalev, const int* __restrict__ fsp,
        int N, int K, size_t obase) {
  int tid = threadIdx.x;
  int lane = tid & 63, w = tid >> 6;
  int wr = w >> 1, wc = w & 1;          // wave -> 64x64 quadrant
  int kq = lane >> 4, lr = lane & 15;
  int bm = blockIdx.y * 128, bn = blockIdx.x * 128;
  f32x4 acc[4][4] = {};

  if constexpr (ABITS) {
    // K = 256 fixed for spike GEMMs.
    __shared__ __align__(16) short lut[256][8];
    {
      short8 e;
      #pragma unroll
      for (int j = 0; j < 8; j++) e[j] = ((tid >> j) & 1) ? (short)0x3F80 : (short)0;
      *(short8*)&lut[tid][0] = e;
    }
    const u32* Abits = (const u32*)Av;
    u32 ab[4][8];
    #pragma unroll
    for (int i = 0; i < 4; i++) {
      const u32* rp = &Abits[(size_t)(bm + wr * 64 + i * 16 + lr) * 8];
      *(u32x4*)&ab[i][0] = *(const u32x4*)&rp[0];
      *(u32x4*)&ab[i][4] = *(const u32x4*)&rp[4];
    }
    __syncthreads();
    #pragma unroll
    for (int s = 0; s < 8; s++) {        // k0 = s*32
      short8 af[4], bf[4];
      #pragma unroll
      for (int i = 0; i < 4; i++) {
        u32 byte = (ab[i][s] >> (kq * 8)) & 0xFFu;
        af[i] = *(const short8*)&lut[byte][0];
      }
      #pragma unroll
      for (int j = 0; j < 4; j++)
        bf[j] = *(const short8*)&Bt[(size_t)(bn + wc * 64 + j * 16 + lr) * 256 + s * 32 + kq * 8];
      #pragma unroll
      for (int i = 0; i < 4; i++)
        #pragma unroll
        for (int j = 0; j < 4; j++)
          acc[i][j] = __builtin_amdgcn_mfma_f32_16x16x32_bf16(af[i], bf[j], acc[i][j], 0, 0, 0);
    }
  } else {
    const bf16* Ab = (const bf16*)Av;
    for (int k0 = 0; k0 < K; k0 += 32) {
      short8 af[4], bf[4];
      #pragma unroll
      for (int i = 0; i < 4; i++)
        af[i] = *(const short8*)&Ab[(size_t)(bm + wr * 64 + i * 16 + lr) * K + k0 + kq * 8];
      #pragma unroll
      for (int j = 0; j < 4; j++)
        bf[j] = *(const short8*)&Bt[(size_t)(bn + wc * 64 + j * 16 + lr) * K + k0 + kq * 8];
      #pragma unroll
      for (int i = 0; i < 4; i++)
        #pragma unroll
        for (int j = 0; j < 4; j++)
          acc[i][j] = __builtin_amdgcn_mfma_f32_16x16x32_bf16(af[i], bf[j], acc[i][j], 0, 0, 0);
    }
  }

  // epilogue: D layout col=lane&15, row=(lane>>4)*4+r (verified mapping)
  float scl = 0.f;
  int fx = 0, fbias = *fbp;
  if (MODE == 4) { scl = ldin(scalev, 0, *fsp); fx = *fxp; }
  int row0 = bm + wr * 64 + kq * 4;
  int col0 = bn + wc * 64 + lr;
  #pragma unroll
  for (int j = 0; j < 4; j++) {
    int n = col0 + j * 16;
    float bb = ldin(biasv, n, fbias);
    #pragma unroll
    for (int i = 0; i < 4; i++) {
      #pragma unroll
      for (int r = 0; r < 4; r++) {
        int m = row0 + i * 16 + r;
        float v = acc[i][j][r] + bb;
        size_t o = obase + (size_t)m * N + n;
        if (MODE == 2) {
          ((bf16*)O)[o] = __float2bfloat16(gelu_f(v));
        } else if (MODE == 3) {
          ((bf16*)O)[o] = __float2bfloat16(v);
        } else {
          float base = ldin(xinv, o, fx);
          ((float*)O)[o] = base + scl * v;
        }
      }
    }
  }
}

// ---------------- fused FFN v2: out += scl*(gelu(spikes@W1+b1)@W2+b2) ----------------
// 512 blocks x 64 tokens x 8 waves (512 thr). Spikes expanded to bf16 LDS tile ONCE
// (As[kb][row][8], 32 KB) via coalesced u32 + LUT; per 128-hidden chunk:
// phase A (wave -> 16 hidden cols, MFMA from As) -> gelu -> hlds[16][64][8];
// phase B (wave -> 32 out cols, MFMA into persistent acc2). 2 barriers/chunk;
// phase A compute sits BEFORE the hlds-overwrite barrier for cross-chunk overlap.
__global__ void __launch_bounds__(512)
ffn_k(const u64* __restrict__ bits_, const bf16* __restrict__ w1t,
      const void* __restrict__ b1v, const int* __restrict__ f1p,
      const bf16* __restrict__ w2t,
      const void* __restrict__ b2v, const int* __restrict__ f2p,
      float* out, const void* __restrict__ scalev, const int* __restrict__ fsp) {
  __shared__ __align__(16) short lut[256][8];     // 4 KB byte->8xbf16
  __shared__ __align__(16) short As[32][64][8];   // 32 KB expanded spikes [kb][row]
  __shared__ __align__(16) short hlds[16][64][8]; // 16 KB h chunk [64][128]
  int tid = threadIdx.x;            // 512
  int lane = tid & 63, w = tid >> 6;   // 8 waves
  int kq = lane >> 4, lr = lane & 15;
  int m0 = blockIdx.x * 64;
  if (tid < 256) {
    short8 e;
    #pragma unroll
    for (int j = 0; j < 8; j++) e[j] = ((tid >> j) & 1) ? (short)0x3F80 : (short)0;
    *(short8*)&lut[tid][0] = e;
  }
  __syncthreads();
  // ---- expand spikes once: thread t -> row t>>3, u32 word t&7 (kb = 4*(t&7)..+3)
  {
    int row = tid >> 3, word = tid & 7;
    u32 val = ((const u32*)bits_)[(size_t)(m0 + row) * 8 + word];
    #pragma unroll
    for (int q = 0; q < 4; q++) {
      u32 byte = (val >> (q * 8)) & 0xFFu;
      *(short8*)&As[word * 4 + q][row][0] = *(const short8*)&lut[byte][0];
    }
  }
  int f1 = *f1p;
  f32x4 acc2[4][2] = {};
  __syncthreads();

  for (int c = 0; c < 8; c++) {
    // ---- phase A: wave w -> hidden cols c*128 + w*16 .. +15
    f32x4 accA[4] = {};
    #pragma unroll
    for (int s = 0; s < 8; s++) {
      short8 bfw = *(const short8*)&w1t[(size_t)(c * 128 + w * 16 + lr) * 256 + s * 32 + kq * 8];
      #pragma unroll
      for (int i = 0; i < 4; i++) {
        short8 af = *(const short8*)&As[s * 4 + kq][i * 16 + lr][0];
        accA[i] = __builtin_amdgcn_mfma_f32_16x16x32_bf16(af, bfw, accA[i], 0, 0, 0);
      }
    }
    __syncthreads();   // prev chunk's phase B done reading hlds
    {
      int cl = w * 16 + lr;
      float bb = ldin(b1v, c * 128 + cl, f1);
      #pragma unroll
      for (int i = 0; i < 4; i++)
        #pragma unroll
        for (int r = 0; r < 4; r++)
          hlds[cl >> 3][i * 16 + kq * 4 + r][cl & 7] = bf16bits(gelu_f(accA[i][r] + bb));
    }
    __syncthreads();
    // ---- phase B: wave w -> out cols w*32 .. +31
    #pragma unroll
    for (int ks = 0; ks < 4; ks++) {
      short8 bf0 = *(const short8*)&w2t[(size_t)(w * 32 + lr) * 1024 + c * 128 + ks * 32 + kq * 8];
      short8 bf1 = *(const short8*)&w2t[(size_t)(w * 32 + 16 + lr) * 1024 + c * 128 + ks * 32 + kq * 8];
      #pragma unroll
      for (int i = 0; i < 4; i++) {
        short8 af = *(const short8*)&hlds[ks * 4 + kq][i * 16 + lr][0];
        acc2[i][0] = __builtin_amdgcn_mfma_f32_16x16x32_bf16(af, bf0, acc2[i][0], 0, 0, 0);
        acc2[i][1] = __builtin_amdgcn_mfma_f32_16x16x32_bf16(af, bf1, acc2[i][1], 0, 0, 0);
      }
    }
  }

  float scl = ldin(scalev, 0, *fsp);
  int f2 = *f2p;
  #pragma unroll
  for (int j = 0; j < 2; j++) {
    int n = w * 32 + j * 16 + lr;
    float bb = ldin(b2v, n, f2);
    #pragma unroll
    for (int i = 0; i < 4; i++)
      #pragma unroll
      for (int r = 0; r < 4; r++) {
        int row = m0 + i * 16 + kq * 4 + r;
        size_t o = (size_t)row * 256 + n;
        out[o] = out[o] + scl * (acc2[i][j][r] + bb);  // same-thread read-then-write
      }
  }
}

// ---------------- region-mean of spike bits: sreg[512][256] fp32 ----------------
__global__ void regmean_k(const u64* __restrict__ bits, float* __restrict__ sreg) {
  int blk = blockIdx.x;   // 512 regions
  int c = threadIdx.x;    // 256
  float s = 0.f;
  for (int i = 0; i < 64; i++) {
    u64 w = bits[(size_t)(blk * 64 + i) * 4 + (c >> 6)];
    s += (float)((w >> (c & 63)) & 1ull);
  }
  sreg[(size_t)blk * 256 + c] = s * (1.0f / 64.0f);
}

// ---------------- routing projection: qkr[512][512] = sreg @ Wqkv[:, :512] + bqkv ----
__global__ void __launch_bounds__(256)
pgemm_k(const float* __restrict__ A,          // sreg [512][256]
        const void* __restrict__ Bv, const int* __restrict__ fBp,   // Wqkv, row stride 768
        const void* __restrict__ biasv, const int* __restrict__ fbp,
        float* __restrict__ Oq) {             // qkr [512][512]
  int fB = *fBp, fb = *fbp;
  __shared__ float Ast[16][68];
  __shared__ float Bs[16][68];
  int tid = threadIdx.x;
  int bm = blockIdx.y * 64, bn = blockIdx.x * 64;
  int tr = tid >> 4, tc = tid & 15;
  float acc[4][4] = {};
  for (int k0 = 0; k0 < 256; k0 += 16) {
    for (int t = tid; t < 1024; t += 256) {
      int m = t >> 4, k = t & 15;
      Ast[k][m] = A[(size_t)(bm + m) * 256 + k0 + k];
    }
    for (int t = tid; t < 1024; t += 256) {
      int k = t >> 6, n = t & 63;
      Bs[k][n] = ldin(Bv, (size_t)(k0 + k) * 768 + bn + n, fB);
    }
    __syncthreads();
    #pragma unroll
    for (int kk = 0; kk < 16; kk++) {
      float4 a4 = *(const float4*)&Ast[kk][tr * 4];
      float4 b4 = *(const float4*)&Bs[kk][tc * 4];
      float a[4] = {a4.x, a4.y, a4.z, a4.w};
      float b[4] = {b4.x, b4.y, b4.z, b4.w};
      #pragma unroll
      for (int i = 0; i < 4; i++)
        #pragma unroll
        for (int jj = 0; jj < 4; jj++)
          acc[i][jj] += a[i] * b[jj];
    }
    __syncthreads();
  }
  #pragma unroll
  for (int i = 0; i < 4; i++)
    #pragma unroll
    for (int jj = 0; jj < 4; jj++) {
      int n = bn + tc * 4 + jj;
      Oq[(size_t)(bm + tr * 4 + i) * 512 + n] = acc[i][jj] + ldin(biasv, n, fb);
    }
}

// ---------------- affinity + top-4 (ties -> lowest index, matches lax.top_k) ----------------
__global__ void afftopk_k(const float* __restrict__ qkr, int* __restrict__ idx) {
  int blk = blockIdx.x;       // (t*8+b)*16 + r
  int tb = blk >> 4;
  int tid = threadIdx.x;      // 256
  int s_ = tid >> 4, p = tid & 15;
  __shared__ float part[256];
  __shared__ float aff[16];
  const float* qrow = qkr + (size_t)blk * 512;                 // q half
  const float* krow = qkr + (size_t)(tb * 16 + s_) * 512 + 256; // k half
  float acc = 0.f;
  for (int c = p * 16; c < p * 16 + 16; c++) acc += qrow[c] * krow[c];
  part[tid] = acc;
  __syncthreads();
  if (tid < 16) {
    float a = 0.f;
    for (int pp = 0; pp < 16; pp++) a += part[tid * 16 + pp];
    aff[tid] = a;
  }
  __syncthreads();
  if (tid == 0) {
    bool taken[16] = {};
    for (int kk = 0; kk < 4; kk++) {
      float best = -INFINITY; int bi = 0;
      for (int i = 0; i < 16; i++)
        if (!taken[i] && aff[i] > best) { best = aff[i]; bi = i; }
      taken[bi] = true;
      idx[blk * 4 + kk] = bi;
    }
  }
}

// ---------------- MFMA gathered attention per (b_local, r, h) ----------------
__global__ void __launch_bounds__(256)
attn_k(const bf16* __restrict__ qkv, const int* __restrict__ idx,
       bf16* __restrict__ ctx) {
  __shared__ __align__(16) short Ks[256][32];     // 16 KB
  __shared__ __align__(16) short Vs[32][256];     // 16 KB (rotated V^T)
  __shared__ __align__(16) short Ps[4][16][256];  // 32 KB (per-wave P, swizzled)
  int blk = blockIdx.x;             // (b_local*16+r)*8 + h
  int h = blk & 7, br = blk >> 3;
  int b = br >> 4;                  // chunk-local batch
  int tid = threadIdx.x;
  int base = br * 64;               // chunk-local token base
  int r0 = idx[br * 4 + 0], r1 = idx[br * 4 + 1];
  int r2 = idx[br * 4 + 2], r3 = idx[br * 4 + 3];

  #pragma unroll
  for (int c = 0; c < 4; c++) {
    int g = c * 256 + tid;
    int tk = g >> 2, ch = g & 3;
    int rs = tk >> 6;
    int rid = (rs & 2) ? ((rs & 1) ? r3 : r2) : ((rs & 1) ? r1 : r0);
    int gt = b * 1024 + rid * 64 + (tk & 63);
    short8 v = *(const short8*)&qkv[(size_t)gt * 768 + 256 + h * 32 + ch * 8];
    *(short8*)&Ks[tk][ch * 8] = v;
  }
  {
    int tk = tid;
    int rs = tk >> 6;
    int rid = (rs & 2) ? ((rs & 1) ? r3 : r2) : ((rs & 1) ? r1 : r0);
    int gt = b * 1024 + rid * 64 + (tk & 63);
    const bf16* vp = &qkv[(size_t)gt * 768 + 512 + h * 32];
    short vv[32];
    *(short8*)&vv[0]  = *(const short8*)&vp[0];
    *(short8*)&vv[8]  = *(const short8*)&vp[8];
    *(short8*)&vv[16] = *(const short8*)&vp[16];
    *(short8*)&vv[24] = *(const short8*)&vp[24];
    #pragma unroll
    for (int d = 0; d < 32; d++)
      Vs[d][(tk + 8 * d) & 255] = vv[d];
  }
  __syncthreads();

  int w = tid >> 6, lane = tid & 63, kq = lane >> 4, lr = lane & 15;

  short8 qf = *(const short8*)&qkv[(size_t)(base + w * 16 + lr) * 768 + h * 32 + kq * 8];

  f32x4 s[16];
  #pragma unroll
  for (int nt = 0; nt < 16; nt++) {
    short8 kf = *(const short8*)&Ks[nt * 16 + lr][kq * 8];
    f32x4 z = {0.f, 0.f, 0.f, 0.f};
    s[nt] = __builtin_amdgcn_mfma_f32_16x16x32_bf16(qf, kf, z, 0, 0, 0);
  }

  const float cs = 0.17677669529663687f;   // 1/sqrt(32)
  float mx[4] = {-INFINITY, -INFINITY, -INFINITY, -INFINITY};
  #pragma unroll
  for (int nt = 0; nt < 16; nt++)
    #pragma unroll
    for (int r = 0; r < 4; r++) mx[r] = fmaxf(mx[r], s[nt][r]);
  #pragma unroll
  for (int m = 1; m < 16; m <<= 1)
    #pragma unroll
    for (int r = 0; r < 4; r++) mx[r] = fmaxf(mx[r], __shfl_xor(mx[r], m, 64));
  float sum[4] = {0.f, 0.f, 0.f, 0.f};
  #pragma unroll
  for (int nt = 0; nt < 16; nt++)
    #pragma unroll
    for (int r = 0; r < 4; r++) {
      float e = __expf((s[nt][r] - mx[r]) * cs);
      s[nt][r] = e; sum[r] += e;
    }
  #pragma unroll
  for (int m = 1; m < 16; m <<= 1)
    #pragma unroll
    for (int r = 0; r < 4; r++) sum[r] += __shfl_xor(sum[r], m, 64);
  float inv[4];
  #pragma unroll
  for (int r = 0; r < 4; r++) inv[r] = 1.0f / sum[r];

  #pragma unroll
  for (int nt = 0; nt < 16; nt++)
    #pragma unroll
    for (int r = 0; r < 4; r++) {
      int row = kq * 4 + r;
      int col = nt * 16 + lr;
      Ps[w][row][col ^ ((row & 7) << 3)] = bf16bits(s[nt][r] * inv[r]);
    }
  __syncthreads();

  f32x4 o0 = {0.f, 0.f, 0.f, 0.f}, o1 = {0.f, 0.f, 0.f, 0.f};
  #pragma unroll
  for (int kc = 0; kc < 8; kc++) {
    short8 pf = *(const short8*)
        &Ps[w][lr][(kc ^ ((lr >> 2) & 1)) * 32 + (kq ^ (lr & 3)) * 8];
    int d0 = lr, d1 = 16 + lr;
    short8 vf0 = *(const short8*)&Vs[d0][(kc * 32 + kq * 8 + 8 * d0) & 255];
    short8 vf1 = *(const short8*)&Vs[d1][(kc * 32 + kq * 8 + 8 * d1) & 255];
    o0 = __builtin_amdgcn_mfma_f32_16x16x32_bf16(pf, vf0, o0, 0, 0, 0);
    o1 = __builtin_amdgcn_mfma_f32_16x16x32_bf16(pf, vf1, o1, 0, 0, 0);
  }

  #pragma unroll
  for (int r = 0; r < 4; r++) {
    int q = base + w * 16 + kq * 4 + r;
    ctx[(size_t)q * 256 + h * 32 + lr]      = __float2bfloat16(o0[r]);
    ctx[(size_t)q * 256 + h * 32 + 16 + lr] = __float2bfloat16(o1[r]);
  }
}

// ---------------- launch ----------------
extern "C" void kernel_launch(void* const* d_in, const int* in_sizes, int n_in,
                              void* d_out, int out_size, void* d_ws, size_t ws_size,
                              hipStream_t stream) {
  const void* x_in = d_in[0];
  const void* Wqkv = d_in[3];
  const void* bqkv = d_in[4];
  const void* Wo   = d_in[5];
  const void* bo   = d_in[6];
  const void* W1   = d_in[9];
  const void* b1   = d_in[10];
  const void* W2   = d_in[11];
  const void* b2   = d_in[12];
  const void* scale = d_in[13];

  const size_t MISC = 256 + 1048576 + 524288 + 8192 + 1048576 + 2048
                    + 393216 + 131072 + 524288 + 524288;
  int C;  // batches (of 1024 tokens) per attention chunk; 32 = whole tensor
  if      (MISC + (size_t)32 * 2097152 <= ws_size) C = 32;   // ~68.2 MB
  else if (MISC + (size_t)16 * 2097152 <= ws_size) C = 16;   // ~37.7 MB
  else if (MISC + (size_t)8  * 2097152 <= ws_size) C = 8;    // ~20.9 MB
  else if (MISC + (size_t)4  * 2097152 <= ws_size) C = 4;    // ~12.5 MB
  else                                             C = 1;
  size_t r0 = (size_t)C * 2097152;   // qkvb (C*1.5MB) + ctxb (C*0.5MB)

  char* ws = (char*)d_ws;
  int*  flags = (int*)ws;      // [0..13] per-input dtype; [14]=0 (bf16); [15]=1 (fp32)
  char* p = ws + 256;
  bf16* qkvb = (bf16*)p;
  bf16* ctxb = (bf16*)(p + (size_t)C * 1572864);
  p += r0;
  float* qkr  = (float*)p;  p += 1048576;   // [512][512] (q||k routing projections)
  float* sreg = (float*)p;  p += 524288;    // [512][256] region means
  int*   idxb = (int*)p;    p += 8192;
  u64*   bits = (u64*)p;    p += 1048576;   // s1 bits, later s2 bits
  float* gsum = (float*)p;  p += 2048;
  float* gsq  = gsum + 256;
  bf16* wqkvt = (bf16*)p;   p += 393216;    // [768][256]
  bf16* wot   = (bf16*)p;   p += 131072;    // [256][256]
  bf16* w1t   = (bf16*)p;   p += 524288;    // [1024][256]
  bf16* w2t   = (bf16*)p;   p += 524288;    // [256][1024]
  float* out  = (float*)d_out;         // FP32 output: x_mid, then final (in place)
  const int* F14 = flags + 14;         // const bf16 flag (0)

  // ---- dtype probes (one launch) ----
  hipMemsetAsync(flags, 0, 256, stream);
  PtrPack pk;
  for (int i = 0; i < 14; i++) { pk.p[i] = d_in[i]; pk.n[i] = in_sizes[i]; }
  probe_all_k<<<14, 64, 0, stream>>>(pk, flags);

  // ---- one-time weight transpose to bf16 [N][K] (one launch) ----
  wconv_all_k<<<3072, 256, 0, stream>>>(Wqkv, Wo, W1, W2, flags,
                                        wqkvt, wot, w1t, w2t);

  // ---- block 1: BN1 + LIF -> s1 bits ----
  hipMemsetAsync(gsum, 0, 512 * sizeof(float), stream);
  bnstats_k<<<256, 256, 0, stream>>>(x_in, flags + 0, gsum, gsq);
  lif_k<<<MT / 256, 256, 0, stream>>>(x_in, flags + 0, gsum, gsq,
                                      d_in[1], flags + 1, d_in[2], flags + 2, bits);

  // ---- region routing (fp32: exact top-k indices) ----
  regmean_k<<<512, 256, 0, stream>>>(bits, sreg);
  pgemm_k<<<dim3(8, 8), 256, 0, stream>>>(sreg, Wqkv, flags + 3, bqkv, flags + 4, qkr);
  afftopk_k<<<512, 256, 0, stream>>>(qkr, idxb);

  // ---- attention chunks over (t,b) batches: qkv -> attn -> x_mid = x + scl*(ctx@Wo+bo) ----
  for (int gb = 0; gb < 32; gb += C) {
    size_t tok0 = (size_t)gb * 1024;
    dgemm_k<3, 1><<<dim3(6, C * 8), 256, 0, stream>>>(
        (const void*)((const u32*)bits + tok0 * 8), wqkvt,
        bqkv, flags + 4, qkvb, nullptr, F14, nullptr, F14, 768, 256, 0);
    attn_k<<<C * 128, 256, 0, stream>>>(qkvb, idxb + gb * 64, ctxb);
    dgemm_k<4, 0><<<dim3(2, C * 8), 256, 0, stream>>>(
        ctxb, wot, bo, flags + 6, out, x_in, flags + 0,
        scale, flags + 13, 256, 256, tok0 * 256);
  }

  // ---- block 2: BN2 + LIF on x_mid (fp32, in d_out) -> s2 bits ----
  hipMemsetAsync(gsum, 0, 512 * sizeof(float), stream);
  bnstats_k<<<256, 256, 0, stream>>>(out, flags + 15, gsum, gsq);
  lif_k<<<MT / 256, 256, 0, stream>>>(out, flags + 15, gsum, gsq,
                                      d_in[7], flags + 7, d_in[8], flags + 8, bits);

  // ---- fused FFN v2: one launch over all 32768 tokens ----
  ffn_k<<<NTOK / 64, 512, 0, stream>>>(bits, w1t, b1, flags + 10,
                                       w2t, b2, flags + 12,
                                       out, scale, flags + 13);
}